// Round 5
// baseline (2687.977 us; speedup 1.0000x reference)
//
#include <hip/hip_runtime.h>
#include <hip/hip_bf16.h>

// Decoder forward: embed+posenc -> causal self-attn -> LN -> cross-attn(img) -> LN -> vocab proj
// B=8 S=512 D=1024 DI=768 NI=197(pad 224) V=32000. GEMMs bf16 MFMA, f32 accum.
// R5: vocab GEMM -> 2-blocks/CU (64KB LDS ring-2), 16x16x32 zero-conflict pattern,
//     single barrier per K-tile; inter-block overlap fills stage/barrier stalls.

#define DEV __device__ __forceinline__

typedef __bf16 bf16x8 __attribute__((ext_vector_type(8)));
typedef float f32x4 __attribute__((ext_vector_type(4)));
typedef unsigned int u32;
typedef __hip_bfloat16 bf16;

DEV void llds16(const void* g, void* l) {
  __builtin_amdgcn_global_load_lds((const __attribute__((address_space(1))) u32*)g,
                                   (__attribute__((address_space(3))) u32*)l, 16, 0, 0);
}

DEV float wredsum(float v){
#pragma unroll
  for (int o = 32; o; o >>= 1) v += __shfl_xor(v, o, 64);
  return v;
}
DEV float wredmax(float v){
#pragma unroll
  for (int o = 32; o; o >>= 1) v = fmaxf(v, __shfl_xor(v, o, 64));
  return v;
}

DEV void store_out(float* p, float v){ *p = v; }
DEV void store_out(bf16* p, float v){ *p = __float2bfloat16(v); }

// ================= big GEMM: C[M,N] = A[M,K] @ Bt[N,K]^T + bias =================
// Requires: M%256==0, N%256==0, K%32==0, K>=64.
// 256x256 tile, BK=32, 8 waves (2Mx4N), per-wave 128x64 = 8x4 frags of 16x16x32.
// LDS: 2-slot dbuf x (A 16KB + B 16KB) = 64 KiB -> 2 blocks/CU (launch_bounds 512,4).
// Per tile: issue 4 stages of t+1; read frags + MFMA (2 halves); vmcnt(0); ONE barrier.
// T2 swizzle: 16B phys slot = hi ^ ((row>>1)&3), pre-swizzled global source (koff) +
// swizzled ds_read (hi2) -- R2-verified zero bank conflicts. T1 XCD swizzle; T5 setprio.
__global__ __launch_bounds__(512, 4) void gemm256_kernel(
    const bf16* __restrict__ A, const bf16* __restrict__ Bt, float* __restrict__ C,
    const float* __restrict__ bias, int M, int N, int K, int lda, int ldb, int ldc)
{
  __shared__ alignas(16) char lds[65536];
  const int tid  = threadIdx.x;
  const int wave = tid >> 6, lane = tid & 63;
  const int lo = lane & 15, hi = lane >> 4;
  const int hi2 = hi ^ ((lo >> 1) & 3);            // swizzled 16B slot for ds_read
  const int wr = wave >> 2, wc = wave & 3;
  const int koff = (((lane & 3) ^ ((lane >> 3) & 3)) << 3);  // pre-swizzled global k (write side)

  // T1: XCD-aware bijective block swizzle (vocab grid 2000 % 8 == 0)
  const int nbx = M >> 8;
  const int nwg = nbx * (N >> 8);
  int id = blockIdx.x;
  int g = (nwg & 7) ? id : ((id & 7) * (nwg >> 3) + (id >> 3));
  const int row0 = (g % nbx) * 256, col0 = (g / nbx) * 256;
  const int NT = K >> 5;
  const int srow = lane >> 2;

  auto stageA = [&](int t) {
    char* base = lds + (t & 1) * 32768;
    const int kk = (t << 5) + koff;
#pragma unroll
    for (int j = 0; j < 2; j++) {
      const int seg = j * 8 + wave;
      llds16(A + (long)(row0 + seg * 16 + srow) * lda + kk, base + seg * 1024);
    }
  };
  auto stageB = [&](int t) {
    char* base = lds + (t & 1) * 32768 + 16384;
    const int kk = (t << 5) + koff;
#pragma unroll
    for (int j = 0; j < 2; j++) {
      const int seg = j * 8 + wave;
      llds16(Bt + (long)(col0 + seg * 16 + srow) * ldb + kk, base + seg * 1024);
    }
  };

  f32x4 acc[8][4] = {};

  // prologue: stage tile 0, drain, sync.
  stageA(0); stageB(0);
  asm volatile("s_waitcnt vmcnt(0)" ::: "memory");
  __builtin_amdgcn_s_barrier();
  __builtin_amdgcn_sched_barrier(0);

  for (int t = 0; t < NT; t++) {
    const char* As = lds + (t & 1) * 32768;
    const char* Bs = As + 16384;
    // issue next tile's staging first: latency hides under this tile's LDS reads + MFMA
    if (t + 1 < NT) { stageA(t + 1); stageB(t + 1); }
    bf16x8 af[4], bfv[4];
#pragma unroll
    for (int n = 0; n < 4; n++)
      bfv[n] = *(const bf16x8*)(Bs + ((wc * 64 + n * 16 + lo) << 6) + (hi2 << 4));
#pragma unroll
    for (int m = 0; m < 4; m++)
      af[m] = *(const bf16x8*)(As + ((wr * 128 + m * 16 + lo) << 6) + (hi2 << 4));
    __builtin_amdgcn_s_setprio(1);
#pragma unroll
    for (int m = 0; m < 4; m++)
#pragma unroll
      for (int n = 0; n < 4; n++)
        acc[m][n] = __builtin_amdgcn_mfma_f32_16x16x32_bf16(af[m], bfv[n], acc[m][n], 0, 0, 0);
    __builtin_amdgcn_s_setprio(0);
#pragma unroll
    for (int m = 0; m < 4; m++)
      af[m] = *(const bf16x8*)(As + ((wr * 128 + (m + 4) * 16 + lo) << 6) + (hi2 << 4));
    __builtin_amdgcn_s_setprio(1);
#pragma unroll
    for (int m = 0; m < 4; m++)
#pragma unroll
      for (int n = 0; n < 4; n++)
        acc[m + 4][n] = __builtin_amdgcn_mfma_f32_16x16x32_bf16(af[m], bfv[n], acc[m + 4][n], 0, 0, 0);
    __builtin_amdgcn_s_setprio(0);
    __builtin_amdgcn_sched_barrier(0);
    asm volatile("s_waitcnt vmcnt(0)" ::: "memory");
    __builtin_amdgcn_sched_barrier(0);
    __builtin_amdgcn_s_barrier();
    __builtin_amdgcn_sched_barrier(0);
  }

#pragma unroll
  for (int m = 0; m < 8; m++) {
    const int r = row0 + wr * 128 + m * 16 + hi * 4;
#pragma unroll
    for (int n = 0; n < 4; n++) {
      const int c = col0 + wc * 64 + n * 16 + lo;
      const float bb = bias ? bias[c] : 0.0f;
#pragma unroll
      for (int j = 0; j < 4; j++)
        C[(long)(r + j) * ldc + c] = acc[m][n][j] + bb;
    }
  }
}

// ---------------- GEMM: C[M,N] = A[M,K] @ Bt[N,K]^T (+bias[N]) ----------------
// 128x128 tile, BK=32, 4 waves (2x2), T2-swizzled (bank conflicts = 0).
template<typename OutT>
__global__ __launch_bounds__(256) void gemm_bt_kernel(
    const bf16* __restrict__ A, const bf16* __restrict__ Bt, OutT* __restrict__ C,
    const float* __restrict__ bias, int M, int N, int K,
    int lda, int ldb, int ldc, long sA, long sB, long sC)
{
  A  += (long)blockIdx.z * sA;
  Bt += (long)blockIdx.z * sB;
  C  += (long)blockIdx.z * sC;
  __shared__ alignas(16) bf16 As[128*32];
  __shared__ alignas(16) bf16 Bs[128*32];
  const int tid = threadIdx.x;
  const int wave = tid >> 6, lane = tid & 63;
  const int lo = lane & 15, hi = lane >> 4;
  const int hi2 = hi ^ ((lo >> 1) & 3);
  const int wr = wave >> 1, wc = wave & 1;
  const int row0 = blockIdx.x * 128, col0 = blockIdx.y * 128;
  const int srow  = lane >> 2;
  const int skoff = (((lane & 3) ^ ((lane >> 3) & 3)) << 3);

  f32x4 acc[4][4] = {};

  for (int k0 = 0; k0 < K; k0 += 32) {
#pragma unroll
    for (int c = 0; c < 2; ++c) {
      const int seg = c*4 + wave;
      int ra = row0 + seg*16 + srow; ra = ra < M ? ra : M-1;
      llds16(A + (long)ra*lda + (k0 + skoff), (char*)As + seg*1024);
      int rb = col0 + seg*16 + srow; rb = rb < N ? rb : N-1;
      llds16(Bt + (long)rb*ldb + (k0 + skoff), (char*)Bs + seg*1024);
    }
    __syncthreads();
    bf16x8 af[4], bfv[4];
#pragma unroll
    for (int m = 0; m < 4; m++)
      af[m] = *(const bf16x8*)((const char*)As + (wr*64 + m*16 + lo)*64 + hi2*16);
#pragma unroll
    for (int n = 0; n < 4; n++)
      bfv[n] = *(const bf16x8*)((const char*)Bs + (wc*64 + n*16 + lo)*64 + hi2*16);
#pragma unroll
    for (int m = 0; m < 4; m++)
#pragma unroll
      for (int n = 0; n < 4; n++)
        acc[m][n] = __builtin_amdgcn_mfma_f32_16x16x32_bf16(af[m], bfv[n], acc[m][n], 0, 0, 0);
    __syncthreads();
  }

#pragma unroll
  for (int m = 0; m < 4; m++) {
    const int rbase = row0 + wr*64 + m*16 + hi*4;
#pragma unroll
    for (int n = 0; n < 4; n++) {
      const int cc = col0 + wc*64 + n*16 + lo;
      if (cc >= N) continue;
      const float bb = bias ? bias[cc] : 0.0f;
#pragma unroll
      for (int j = 0; j < 4; j++) {
        const int rr = rbase + j;
        if (rr < M) store_out(&C[(long)rr*ldc + cc], acc[m][n][j] + bb);
      }
    }
  }
}

// ---------------- weight prep: W[K,N] f32 -> Wt[N,K] bf16, z-indexed up to 4 pairs ----------------
__global__ __launch_bounds__(256) void wprep4_kernel(
    const float* W0, const float* W1, const float* W2, const float* W3,
    bf16* T0, bf16* T1, bf16* T2, bf16* T3, int K, int N)
{
  const int z = blockIdx.z;
  const float* W = z == 0 ? W0 : z == 1 ? W1 : z == 2 ? W2 : W3;
  bf16* T = z == 0 ? T0 : z == 1 ? T1 : z == 2 ? T2 : T3;
  __shared__ bf16 t[32][33];
  const int k0 = blockIdx.x * 32, n0 = blockIdx.y * 32;
  const int tx = threadIdx.x & 31, ty = threadIdx.x >> 5;
#pragma unroll
  for (int i = 0; i < 4; i++)
    t[ty + i*8][tx] = __float2bfloat16(W[(long)(k0 + ty + i*8)*N + n0 + tx]);
  __syncthreads();
#pragma unroll
  for (int i = 0; i < 4; i++)
    T[(long)(n0 + ty + i*8)*K + k0 + tx] = t[tx][ty + i*8];
}

// ---------------- bf16 transpose with zero-pad: in[R x Cc (ld inLD)] -> out[Cc x outLD] ----------------
__global__ __launch_bounds__(256) void transpose_pad_kernel(
    const bf16* __restrict__ in, bf16* __restrict__ out,
    int R, int Cc, int inLD, int outLD, long inBatch, long outBatch)
{
  in  += (long)blockIdx.z * inBatch;
  out += (long)blockIdx.z * outBatch;
  __shared__ bf16 t[32][33];
  const int r0 = blockIdx.x * 32, c0 = blockIdx.y * 32;
  const int tx = threadIdx.x & 31, ty = threadIdx.x >> 5;
#pragma unroll
  for (int i = 0; i < 4; i++) {
    const int r = r0 + ty + i*8;
    bf16 v = __float2bfloat16(0.0f);
    if (r < R) v = in[(long)r*inLD + c0 + tx];
    t[ty + i*8][tx] = v;
  }
  __syncthreads();
#pragma unroll
  for (int i = 0; i < 4; i++) {
    const int oc = r0 + tx;
    const int orow = c0 + ty + i*8;
    if (oc < outLD) out[(long)orow*outLD + oc] = t[tx][ty + i*8];
  }
}

// ---------------- bias concat (up to 3) ----------------
__global__ __launch_bounds__(256) void concat_bias_kernel(
    const float* a, const float* b, const float* c, int n1, int n2, int n3, float* out)
{
  const int i = blockIdx.x * 256 + threadIdx.x;
  if (i >= n1 + n2 + n3) return;
  out[i] = i < n1 ? a[i] : (i < n1 + n2 ? b[i - n1] : c[i - n1 - n2]);
}

// ---------------- embedding + sinusoidal positional encoding ----------------
__global__ __launch_bounds__(256) void embed_kernel(
    const int* __restrict__ tok, const float* __restrict__ tbl,
    float* __restrict__ xf, bf16* __restrict__ xb)
{
  const int row = blockIdx.x;
  const int s = row & 511;
  const float pos = (float)s;
  const float* te = tbl + (long)tok[row] * 1024;
  const int d0 = threadIdx.x * 4;
  float4 v = *(const float4*)(te + d0);
  float o[4] = {v.x, v.y, v.z, v.w};
#pragma unroll
  for (int k = 0; k < 4; k++) {
    const int d = d0 + k;
    const int i2 = d & ~1;
    const float ang = pos * powf(10000.0f, -(float)i2 * (1.0f/1024.0f));
    o[k] += (d & 1) ? cosf(ang) : sinf(ang);
  }
  *(float4*)(xf + (long)row*1024 + d0) = make_float4(o[0], o[1], o[2], o[3]);
#pragma unroll
  for (int k = 0; k < 4; k++) xb[(long)row*1024 + d0 + k] = __float2bfloat16(o[k]);
}

// ---------------- f32 -> bf16 copy ----------------
__global__ __launch_bounds__(256) void cvt_bf16_kernel(const float* __restrict__ in, bf16* __restrict__ out, long n)
{
  long i = (long)blockIdx.x * blockDim.x + threadIdx.x;
  if (i < n) out[i] = __float2bfloat16(in[i]);
}

// ---------------- causal softmax over scores [B*S rows][512] ----------------
__global__ __launch_bounds__(64) void softmax_causal_kernel(
    const float* __restrict__ Sc, bf16* __restrict__ P)
{
  const int row = blockIdx.x;
  const int q = row & 511;
  const float* srow = Sc + (long)row * 512;
  bf16* prow = P + (long)row * 512;
  const int lane = threadIdx.x;
  const float scale = 0.03125f;
  float mx = -1e30f;
  for (int j = lane; j <= q; j += 64) mx = fmaxf(mx, srow[j]);
  mx = wredmax(mx);
  float sum = 0.0f;
  for (int j = lane; j <= q; j += 64) sum += expf((srow[j] - mx) * scale);
  sum = wredsum(sum);
  const float inv = 1.0f / sum;
  for (int j = lane; j < 512; j += 64) {
    float p = (j <= q) ? expf((srow[j] - mx) * scale) * inv : 0.0f;
    prow[j] = __float2bfloat16(p);
  }
}

// ---------------- cross softmax: rows of 197 valid (ld 224) ----------------
__global__ __launch_bounds__(64) void softmax_cross_kernel(
    const float* __restrict__ Sc, bf16* __restrict__ P)
{
  const int row = blockIdx.x;
  const float* srow = Sc + (long)row * 224;
  bf16* prow = P + (long)row * 224;
  const int lane = threadIdx.x;
  const float scale = 0.03125f;
  float mx = -1e30f;
  for (int j = lane; j < 197; j += 64) mx = fmaxf(mx, srow[j]);
  mx = wredmax(mx);
  float sum = 0.0f;
  for (int j = lane; j < 197; j += 64) sum += expf((srow[j] - mx) * scale);
  sum = wredsum(sum);
  const float inv = 1.0f / sum;
  for (int j = lane; j < 224; j += 64) {
    float p = (j < 197) ? expf((srow[j] - mx) * scale) * inv : 0.0f;
    prow[j] = __float2bfloat16(p);
  }
}

// ---------------- add residual + LayerNorm; write f32 (optional) + bf16 ----------------
__global__ __launch_bounds__(256) void add_ln_kernel(
    const float* __restrict__ Acc, const float* __restrict__ Res,
    const float* __restrict__ g, const float* __restrict__ b,
    float* __restrict__ outf, bf16* __restrict__ outb)
{
  const int row = blockIdx.x;
  const float* a = Acc + (long)row * 1024;
  const float* r = Res + (long)row * 1024;
  float vals[4], s = 0.0f, ss = 0.0f;
#pragma unroll
  for (int i = 0; i < 4; i++) {
    const int d = threadIdx.x + i*256;
    const float v = a[d] + r[d];
    vals[i] = v; s += v; ss += v*v;
  }
  s = wredsum(s); ss = wredsum(ss);
  __shared__ float sh[8];
  const int wave = threadIdx.x >> 6, lane = threadIdx.x & 63;
  if (lane == 0) { sh[wave] = s; sh[wave+4] = ss; }
  __syncthreads();
  s  = sh[0] + sh[1] + sh[2] + sh[3];
  ss = sh[4] + sh[5] + sh[6] + sh[7];
  const float mean = s * (1.0f/1024.0f);
  const float var  = ss * (1.0f/1024.0f) - mean*mean;
  const float inv  = rsqrtf(var + 1e-5f);
#pragma unroll
  for (int i = 0; i < 4; i++) {
    const int d = threadIdx.x + i*256;
    const float y = (vals[i] - mean) * inv * g[d] + b[d];
    if (outf) outf[(long)row*1024 + d] = y;
    outb[(long)row*1024 + d] = __float2bfloat16(y);
  }
}

// =======================================================================================
extern "C" void kernel_launch(void* const* d_in, const int* in_sizes, int n_in,
                              void* d_out, int out_size, void* d_ws, size_t ws_size,
                              hipStream_t stream) {
  const int*   tokens = (const int*)  d_in[0];
  const float* img    = (const float*)d_in[1];
  const float* emb    = (const float*)d_in[2];
  const float* Wq1    = (const float*)d_in[3];
  const float* bq1    = (const float*)d_in[4];
  const float* Wk1    = (const float*)d_in[5];
  const float* bk1    = (const float*)d_in[6];
  const float* Wv1    = (const float*)d_in[7];
  const float* bv1    = (const float*)d_in[8];
  const float* g1     = (const float*)d_in[9];
  const float* b1     = (const float*)d_in[10];
  const float* Wq2    = (const float*)d_in[11];
  const float* bq2    = (const float*)d_in[12];
  const float* Wk2    = (const float*)d_in[13];
  const float* bk2    = (const float*)d_in[14];
  const float* Wv2    = (const float*)d_in[15];
  const float* bv2    = (const float*)d_in[16];
  const float* g2     = (const float*)d_in[17];
  const float* b2     = (const float*)d_in[18];
  const float* Wp     = (const float*)d_in[19];
  const float* bp     = (const float*)d_in[20];
  float* out = (float*)d_out;

  const int B = 8, S = 512, D = 1024, DI = 768, NI = 197, NIP = 224, V = 32000;
  const int M = B * S;          // 4096
  const int MI = B * NI;        // 1576

  char* ws = (char*)d_ws;
  size_t off = 0;
  auto alloc = [&](size_t bytes) -> char* {
    char* p = ws + off; off += (bytes + 255) & ~(size_t)255; return p;
  };
  // NOTE: Wq1t/Wk1t/Wv1t contiguous (each 2MB, 256-aligned) -> fused QKV B-matrix [3072][1024].
  //       Wk2t/Wv2t contiguous (each 1.5MB) -> fused KV2 B-matrix [2048][768].
  bf16* Wq1t = (bf16*)alloc((size_t)D*D*2);
  bf16* Wk1t = (bf16*)alloc((size_t)D*D*2);
  bf16* Wv1t = (bf16*)alloc((size_t)D*D*2);
  bf16* Wq2t = (bf16*)alloc((size_t)D*D*2);
  bf16* Wk2t = (bf16*)alloc((size_t)D*DI*2);
  bf16* Wv2t = (bf16*)alloc((size_t)D*DI*2);
  bf16* Wpt  = (bf16*)alloc((size_t)V*D*2);
  float* bqkv= (float*)alloc((size_t)3*D*4);
  float* bkv2= (float*)alloc((size_t)2*D*4);
  float* xf  = (float*)alloc((size_t)M*D*4);
  bf16*  xb  = (bf16*) alloc((size_t)M*D*2);
  bf16*  imgb= (bf16*) alloc((size_t)MI*DI*2);
  bf16*  QKV = (bf16*) alloc((size_t)M*3*D*2);   // [M][3072]: Q | K | V
  bf16*  Vt  = (bf16*) alloc((size_t)M*D*2);
  float* sc1 = (float*)alloc((size_t)B*S*S*4);
  bf16*  P1  = (bf16*) alloc((size_t)B*S*S*2);
  float* ao1 = (float*)alloc((size_t)M*D*4);
  float* x2f = (float*)alloc((size_t)M*D*4);
  bf16*  x2b = (bf16*) alloc((size_t)M*D*2);
  bf16*  Q2  = (bf16*) alloc((size_t)M*D*2);
  bf16*  KV2 = (bf16*) alloc((size_t)MI*2*D*2);  // [MI][2048]: K2 | V2
  bf16*  V2t = (bf16*) alloc((size_t)B*D*NIP*2);
  float* sc2 = (float*)alloc((size_t)B*S*NIP*4);
  bf16*  P2  = (bf16*) alloc((size_t)B*S*NIP*2);
  float* ao2 = (float*)alloc((size_t)M*D*4);
  bf16*  x3b = (bf16*) alloc((size_t)M*D*2);
  (void)ws_size; (void)in_sizes; (void)n_in; (void)out_size;

  // --- weight prep (f32 [K,N] -> bf16 [N,K]) ---
  wprep4_kernel<<<dim3(D/32,  D/32, 4), 256, 0, stream>>>(Wq1, Wk1, Wv1, Wq2, Wq1t, Wk1t, Wv1t, Wq2t, D, D);
  wprep4_kernel<<<dim3(DI/32, D/32, 2), 256, 0, stream>>>(Wk2, Wv2, nullptr, nullptr, Wk2t, Wv2t, nullptr, nullptr, DI, D);
  wprep4_kernel<<<dim3(D/32,  V/32, 1), 256, 0, stream>>>(Wp, nullptr, nullptr, nullptr, Wpt, nullptr, nullptr, nullptr, D, V);
  concat_bias_kernel<<<(3*D+255)/256, 256, 0, stream>>>(bq1, bk1, bv1, D, D, D, bqkv);
  concat_bias_kernel<<<(2*D+255)/256, 256, 0, stream>>>(bk2, bv2, nullptr, D, D, 0, bkv2);

  // --- embed + img convert ---
  embed_kernel<<<M, 256, 0, stream>>>(tokens, emb, xf, xb);
  {
    long n = (long)MI * DI;
    cvt_bf16_kernel<<<(int)((n + 255)/256), 256, 0, stream>>>(img, imgb, n);
  }

  auto gemmF = [&](const bf16* A, const bf16* Bt, float* C, const float* bias,
                   int m, int n, int k, int lda, int ldb, int ldc,
                   long sA, long sB, long sC, int batch) {
    dim3 g((m+127)/128, (n+127)/128, batch);
    gemm_bt_kernel<float><<<g, 256, 0, stream>>>(A, Bt, C, bias, m, n, k, lda, ldb, ldc, sA, sB, sC);
  };
  auto gemmB = [&](const bf16* A, const bf16* Bt, bf16* C, const float* bias,
                   int m, int n, int k, int lda, int ldb, int ldc,
                   long sA, long sB, long sC, int batch) {
    dim3 g((m+127)/128, (n+127)/128, batch);
    gemm_bt_kernel<bf16><<<g, 256, 0, stream>>>(A, Bt, C, bias, m, n, k, lda, ldb, ldc, sA, sB, sC);
  };

  // --- block 1: causal self-attention (fused QKV GEMM: N=3072) ---
  gemmB(xb, Wq1t, QKV, bqkv, M, 3*D, D, D, D, 3*D, 0, 0, 0, 1);
  transpose_pad_kernel<<<dim3(S/32, D/32, B), 256, 0, stream>>>(
      QKV + 2*D, Vt, S, D, 3*D, S, (long)S*3*D, (long)D*S);
  gemmF(QKV, QKV + D, sc1, nullptr, S, S, D, 3*D, 3*D, S, (long)S*3*D, (long)S*3*D, (long)S*S, B);
  softmax_causal_kernel<<<M, 64, 0, stream>>>(sc1, P1);
  gemmF(P1, Vt, ao1, nullptr, S, D, S, S, S, D, (long)S*S, (long)D*S, (long)S*D, B);
  add_ln_kernel<<<M, 256, 0, stream>>>(ao1, xf, g1, b1, x2f, x2b);

  // --- block 2: cross-attention over image tokens (fused K2V2 GEMM: N=2048) ---
  gemmB(x2b, Wq2t, Q2, bq2, M, D, D, D, D, D, 0, 0, 0, 1);
  gemmB(imgb, Wk2t, KV2, bkv2, MI, 2*D, DI, DI, DI, 2*D, 0, 0, 0, 1);
  transpose_pad_kernel<<<dim3((NIP+31)/32, D/32, B), 256, 0, stream>>>(
      KV2 + D, V2t, NI, D, 2*D, NIP, (long)NI*2*D, (long)D*NIP);
  gemmF(Q2, KV2, sc2, nullptr, S, NI, D, D, 2*D, NIP, (long)S*D, (long)NI*2*D, (long)S*NIP, B);
  softmax_cross_kernel<<<M, 64, 0, stream>>>(sc2, P2);
  gemmF(P2, V2t, ao2, nullptr, S, D, NIP, NIP, NIP, D, (long)S*NIP, (long)D*NIP, (long)S*D, B);
  add_ln_kernel<<<M, 256, 0, stream>>>(ao2, x2f, g2, b2, nullptr, x3b);

  // --- vocab projection: 256x256-tile, 2-blocks/CU pipelined kernel (grid 2000) ---
  {
    dim3 g((M/256) * (V/256));
    gemm256_kernel<<<g, 512, 0, stream>>>(x3b, Wpt, out, bp, M, V, D, D, D, V);
  }
}

// Round 6
// 828.132 us; speedup vs baseline: 3.2458x; 3.2458x over previous
//
#include <hip/hip_runtime.h>
#include <hip/hip_bf16.h>

// Decoder forward: embed+posenc -> causal self-attn -> LN -> cross-attn(img) -> LN -> vocab proj
// B=8 S=512 D=1024 DI=768 NI=197(pad 224) V=32000. GEMMs bf16 MFMA (16x16x32), f32 accum.
// R6: vocab GEMM -> faithful m97 128x128/BK=32 single-buffer structure (3 blocks/CU
//     inter-block overlap) + XCD-chunked grid; R5's reg-capped 2-block attempt reverted.

#define DEV __device__ __forceinline__

typedef __bf16 bf16x8 __attribute__((ext_vector_type(8)));
typedef float f32x4 __attribute__((ext_vector_type(4)));
typedef unsigned int u32;
typedef __hip_bfloat16 bf16;

DEV void llds16(const void* g, void* l) {
  __builtin_amdgcn_global_load_lds((const __attribute__((address_space(1))) u32*)g,
                                   (__attribute__((address_space(3))) u32*)l, 16, 0, 0);
}

DEV float wredsum(float v){
#pragma unroll
  for (int o = 32; o; o >>= 1) v += __shfl_xor(v, o, 64);
  return v;
}
DEV float wredmax(float v){
#pragma unroll
  for (int o = 32; o; o >>= 1) v = fmaxf(v, __shfl_xor(v, o, 64));
  return v;
}

DEV void store_out(float* p, float v){ *p = v; }
DEV void store_out(bf16* p, float v){ *p = __float2bfloat16(v); }

// ================= vocab GEMM: C[M,N] = A[M,K] @ Bt[N,K]^T + bias =================
// m97-faithful: 128x128 tile, BK=32, 4 waves (2x2), single-buffered LDS, 2 barriers/K-step.
// Requires M%128==0, N%128==0, K%32==0. Linear grid with XCD-bijective chunking:
// 32 consecutive swizzled ids share one B-panel (col0) -> per-XCD L2 reuse.
__global__ __launch_bounds__(256) void gemm_vocab_kernel(
    const bf16* __restrict__ A, const bf16* __restrict__ Bt, float* __restrict__ C,
    const float* __restrict__ bias, int M, int N, int K, int lda, int ldb, int ldc)
{
  __shared__ alignas(16) bf16 As[128*32];
  __shared__ alignas(16) bf16 Bs[128*32];
  const int tid = threadIdx.x;
  const int wave = tid >> 6, lane = tid & 63;
  const int lo = lane & 15, hi = lane >> 4;
  const int hi2 = hi ^ ((lo >> 1) & 3);                       // T2 read-side swizzle
  const int wr = wave >> 1, wc = wave & 1;
  const int nbx = M >> 7;
  const int nwg = nbx * (N >> 7);
  const int id = blockIdx.x;
  const int gg = (nwg & 7) ? id : ((id & 7) * (nwg >> 3) + (id >> 3));  // XCD chunking
  const int row0 = (gg % nbx) * 128;                          // row varies fastest: B-panel reuse
  const int col0 = (gg / nbx) * 128;
  const int srow  = lane >> 2;
  const int skoff = (((lane & 3) ^ ((lane >> 3) & 3)) << 3);  // T2 write-side (pre-swizzled global)

  f32x4 acc[4][4] = {};

  for (int k0 = 0; k0 < K; k0 += 32) {
#pragma unroll
    for (int c = 0; c < 2; ++c) {
      const int seg = c*4 + wave;
      llds16(A + (long)(row0 + seg*16 + srow)*lda + (k0 + skoff), (char*)As + seg*1024);
      llds16(Bt + (long)(col0 + seg*16 + srow)*ldb + (k0 + skoff), (char*)Bs + seg*1024);
    }
    __syncthreads();
    bf16x8 af[4], bfv[4];
#pragma unroll
    for (int m = 0; m < 4; m++)
      af[m] = *(const bf16x8*)((const char*)As + (wr*64 + m*16 + lo)*64 + hi2*16);
#pragma unroll
    for (int n = 0; n < 4; n++)
      bfv[n] = *(const bf16x8*)((const char*)Bs + (wc*64 + n*16 + lo)*64 + hi2*16);
#pragma unroll
    for (int m = 0; m < 4; m++)
#pragma unroll
      for (int n = 0; n < 4; n++)
        acc[m][n] = __builtin_amdgcn_mfma_f32_16x16x32_bf16(af[m], bfv[n], acc[m][n], 0, 0, 0);
    __syncthreads();
  }

#pragma unroll
  for (int m = 0; m < 4; m++) {
    const int rbase = row0 + wr*64 + m*16 + hi*4;
#pragma unroll
    for (int n = 0; n < 4; n++) {
      const int cc = col0 + wc*64 + n*16 + lo;
      const float bb = bias ? bias[cc] : 0.0f;
#pragma unroll
      for (int j = 0; j < 4; j++)
        C[(long)(rbase + j)*ldc + cc] = acc[m][n][j] + bb;
    }
  }
}

// ---------------- GEMM: C[M,N] = A[M,K] @ Bt[N,K]^T (+bias[N]) ----------------
// 128x128 tile, BK=32, 4 waves (2x2), T2-swizzled, bounds-guarded (general shapes).
template<typename OutT>
__global__ __launch_bounds__(256) void gemm_bt_kernel(
    const bf16* __restrict__ A, const bf16* __restrict__ Bt, OutT* __restrict__ C,
    const float* __restrict__ bias, int M, int N, int K,
    int lda, int ldb, int ldc, long sA, long sB, long sC)
{
  A  += (long)blockIdx.z * sA;
  Bt += (long)blockIdx.z * sB;
  C  += (long)blockIdx.z * sC;
  __shared__ alignas(16) bf16 As[128*32];
  __shared__ alignas(16) bf16 Bs[128*32];
  const int tid = threadIdx.x;
  const int wave = tid >> 6, lane = tid & 63;
  const int lo = lane & 15, hi = lane >> 4;
  const int hi2 = hi ^ ((lo >> 1) & 3);
  const int wr = wave >> 1, wc = wave & 1;
  const int row0 = blockIdx.x * 128, col0 = blockIdx.y * 128;
  const int srow  = lane >> 2;
  const int skoff = (((lane & 3) ^ ((lane >> 3) & 3)) << 3);

  f32x4 acc[4][4] = {};

  for (int k0 = 0; k0 < K; k0 += 32) {
#pragma unroll
    for (int c = 0; c < 2; ++c) {
      const int seg = c*4 + wave;
      int ra = row0 + seg*16 + srow; ra = ra < M ? ra : M-1;
      llds16(A + (long)ra*lda + (k0 + skoff), (char*)As + seg*1024);
      int rb = col0 + seg*16 + srow; rb = rb < N ? rb : N-1;
      llds16(Bt + (long)rb*ldb + (k0 + skoff), (char*)Bs + seg*1024);
    }
    __syncthreads();
    bf16x8 af[4], bfv[4];
#pragma unroll
    for (int m = 0; m < 4; m++)
      af[m] = *(const bf16x8*)((const char*)As + (wr*64 + m*16 + lo)*64 + hi2*16);
#pragma unroll
    for (int n = 0; n < 4; n++)
      bfv[n] = *(const bf16x8*)((const char*)Bs + (wc*64 + n*16 + lo)*64 + hi2*16);
#pragma unroll
    for (int m = 0; m < 4; m++)
#pragma unroll
      for (int n = 0; n < 4; n++)
        acc[m][n] = __builtin_amdgcn_mfma_f32_16x16x32_bf16(af[m], bfv[n], acc[m][n], 0, 0, 0);
    __syncthreads();
  }

#pragma unroll
  for (int m = 0; m < 4; m++) {
    const int rbase = row0 + wr*64 + m*16 + hi*4;
#pragma unroll
    for (int n = 0; n < 4; n++) {
      const int cc = col0 + wc*64 + n*16 + lo;
      if (cc >= N) continue;
      const float bb = bias ? bias[cc] : 0.0f;
#pragma unroll
      for (int j = 0; j < 4; j++) {
        const int rr = rbase + j;
        if (rr < M) store_out(&C[(long)rr*ldc + cc], acc[m][n][j] + bb);
      }
    }
  }
}

// ---------------- weight prep: W[K,N] f32 -> Wt[N,K] bf16, z-indexed up to 4 pairs ----------------
__global__ __launch_bounds__(256) void wprep4_kernel(
    const float* W0, const float* W1, const float* W2, const float* W3,
    bf16* T0, bf16* T1, bf16* T2, bf16* T3, int K, int N)
{
  const int z = blockIdx.z;
  const float* W = z == 0 ? W0 : z == 1 ? W1 : z == 2 ? W2 : W3;
  bf16* T = z == 0 ? T0 : z == 1 ? T1 : z == 2 ? T2 : T3;
  __shared__ bf16 t[32][33];
  const int k0 = blockIdx.x * 32, n0 = blockIdx.y * 32;
  const int tx = threadIdx.x & 31, ty = threadIdx.x >> 5;
#pragma unroll
  for (int i = 0; i < 4; i++)
    t[ty + i*8][tx] = __float2bfloat16(W[(long)(k0 + ty + i*8)*N + n0 + tx]);
  __syncthreads();
#pragma unroll
  for (int i = 0; i < 4; i++)
    T[(long)(n0 + ty + i*8)*K + k0 + tx] = t[tx][ty + i*8];
}

// ---------------- bf16 transpose with zero-pad: in[R x Cc (ld inLD)] -> out[Cc x outLD] ----------------
__global__ __launch_bounds__(256) void transpose_pad_kernel(
    const bf16* __restrict__ in, bf16* __restrict__ out,
    int R, int Cc, int inLD, int outLD, long inBatch, long outBatch)
{
  in  += (long)blockIdx.z * inBatch;
  out += (long)blockIdx.z * outBatch;
  __shared__ bf16 t[32][33];
  const int r0 = blockIdx.x * 32, c0 = blockIdx.y * 32;
  const int tx = threadIdx.x & 31, ty = threadIdx.x >> 5;
#pragma unroll
  for (int i = 0; i < 4; i++) {
    const int r = r0 + ty + i*8;
    bf16 v = __float2bfloat16(0.0f);
    if (r < R) v = in[(long)r*inLD + c0 + tx];
    t[ty + i*8][tx] = v;
  }
  __syncthreads();
#pragma unroll
  for (int i = 0; i < 4; i++) {
    const int oc = r0 + tx;
    const int orow = c0 + ty + i*8;
    if (oc < outLD) out[(long)orow*outLD + oc] = t[tx][ty + i*8];
  }
}

// ---------------- bias concat (up to 3) ----------------
__global__ __launch_bounds__(256) void concat_bias_kernel(
    const float* a, const float* b, const float* c, int n1, int n2, int n3, float* out)
{
  const int i = blockIdx.x * 256 + threadIdx.x;
  if (i >= n1 + n2 + n3) return;
  out[i] = i < n1 ? a[i] : (i < n1 + n2 ? b[i - n1] : c[i - n1 - n2]);
}

// ---------------- embedding + sinusoidal positional encoding ----------------
__global__ __launch_bounds__(256) void embed_kernel(
    const int* __restrict__ tok, const float* __restrict__ tbl,
    float* __restrict__ xf, bf16* __restrict__ xb)
{
  const int row = blockIdx.x;
  const int s = row & 511;
  const float pos = (float)s;
  const float* te = tbl + (long)tok[row] * 1024;
  const int d0 = threadIdx.x * 4;
  float4 v = *(const float4*)(te + d0);
  float o[4] = {v.x, v.y, v.z, v.w};
#pragma unroll
  for (int k = 0; k < 4; k++) {
    const int d = d0 + k;
    const int i2 = d & ~1;
    const float ang = pos * powf(10000.0f, -(float)i2 * (1.0f/1024.0f));
    o[k] += (d & 1) ? cosf(ang) : sinf(ang);
  }
  *(float4*)(xf + (long)row*1024 + d0) = make_float4(o[0], o[1], o[2], o[3]);
#pragma unroll
  for (int k = 0; k < 4; k++) xb[(long)row*1024 + d0 + k] = __float2bfloat16(o[k]);
}

// ---------------- f32 -> bf16 copy ----------------
__global__ __launch_bounds__(256) void cvt_bf16_kernel(const float* __restrict__ in, bf16* __restrict__ out, long n)
{
  long i = (long)blockIdx.x * blockDim.x + threadIdx.x;
  if (i < n) out[i] = __float2bfloat16(in[i]);
}

// ---------------- causal softmax over scores [B*S rows][512] ----------------
__global__ __launch_bounds__(64) void softmax_causal_kernel(
    const float* __restrict__ Sc, bf16* __restrict__ P)
{
  const int row = blockIdx.x;
  const int q = row & 511;
  const float* srow = Sc + (long)row * 512;
  bf16* prow = P + (long)row * 512;
  const int lane = threadIdx.x;
  const float scale = 0.03125f;
  float mx = -1e30f;
  for (int j = lane; j <= q; j += 64) mx = fmaxf(mx, srow[j]);
  mx = wredmax(mx);
  float sum = 0.0f;
  for (int j = lane; j <= q; j += 64) sum += expf((srow[j] - mx) * scale);
  sum = wredsum(sum);
  const float inv = 1.0f / sum;
  for (int j = lane; j < 512; j += 64) {
    float p = (j <= q) ? expf((srow[j] - mx) * scale) * inv : 0.0f;
    prow[j] = __float2bfloat16(p);
  }
}

// ---------------- cross softmax: rows of 197 valid (ld 224) ----------------
__global__ __launch_bounds__(64) void softmax_cross_kernel(
    const float* __restrict__ Sc, bf16* __restrict__ P)
{
  const int row = blockIdx.x;
  const float* srow = Sc + (long)row * 224;
  bf16* prow = P + (long)row * 224;
  const int lane = threadIdx.x;
  const float scale = 0.03125f;
  float mx = -1e30f;
  for (int j = lane; j < 197; j += 64) mx = fmaxf(mx, srow[j]);
  mx = wredmax(mx);
  float sum = 0.0f;
  for (int j = lane; j < 197; j += 64) sum += expf((srow[j] - mx) * scale);
  sum = wredsum(sum);
  const float inv = 1.0f / sum;
  for (int j = lane; j < 224; j += 64) {
    float p = (j < 197) ? expf((srow[j] - mx) * scale) * inv : 0.0f;
    prow[j] = __float2bfloat16(p);
  }
}

// ---------------- add residual + LayerNorm; write f32 (optional) + bf16 ----------------
__global__ __launch_bounds__(256) void add_ln_kernel(
    const float* __restrict__ Acc, const float* __restrict__ Res,
    const float* __restrict__ g, const float* __restrict__ b,
    float* __restrict__ outf, bf16* __restrict__ outb)
{
  const int row = blockIdx.x;
  const float* a = Acc + (long)row * 1024;
  const float* r = Res + (long)row * 1024;
  float vals[4], s = 0.0f, ss = 0.0f;
#pragma unroll
  for (int i = 0; i < 4; i++) {
    const int d = threadIdx.x + i*256;
    const float v = a[d] + r[d];
    vals[i] = v; s += v; ss += v*v;
  }
  s = wredsum(s); ss = wredsum(ss);
  __shared__ float sh[8];
  const int wave = threadIdx.x >> 6, lane = threadIdx.x & 63;
  if (lane == 0) { sh[wave] = s; sh[wave+4] = ss; }
  __syncthreads();
  s  = sh[0] + sh[1] + sh[2] + sh[3];
  ss = sh[4] + sh[5] + sh[6] + sh[7];
  const float mean = s * (1.0f/1024.0f);
  const float var  = ss * (1.0f/1024.0f) - mean*mean;
  const float inv  = rsqrtf(var + 1e-5f);
#pragma unroll
  for (int i = 0; i < 4; i++) {
    const int d = threadIdx.x + i*256;
    const float y = (vals[i] - mean) * inv * g[d] + b[d];
    if (outf) outf[(long)row*1024 + d] = y;
    outb[(long)row*1024 + d] = __float2bfloat16(y);
  }
}

// =======================================================================================
extern "C" void kernel_launch(void* const* d_in, const int* in_sizes, int n_in,
                              void* d_out, int out_size, void* d_ws, size_t ws_size,
                              hipStream_t stream) {
  const int*   tokens = (const int*)  d_in[0];
  const float* img    = (const float*)d_in[1];
  const float* emb    = (const float*)d_in[2];
  const float* Wq1    = (const float*)d_in[3];
  const float* bq1    = (const float*)d_in[4];
  const float* Wk1    = (const float*)d_in[5];
  const float* bk1    = (const float*)d_in[6];
  const float* Wv1    = (const float*)d_in[7];
  const float* bv1    = (const float*)d_in[8];
  const float* g1     = (const float*)d_in[9];
  const float* b1     = (const float*)d_in[10];
  const float* Wq2    = (const float*)d_in[11];
  const float* bq2    = (const float*)d_in[12];
  const float* Wk2    = (const float*)d_in[13];
  const float* bk2    = (const float*)d_in[14];
  const float* Wv2    = (const float*)d_in[15];
  const float* bv2    = (const float*)d_in[16];
  const float* g2     = (const float*)d_in[17];
  const float* b2     = (const float*)d_in[18];
  const float* Wp     = (const float*)d_in[19];
  const float* bp     = (const float*)d_in[20];
  float* out = (float*)d_out;

  const int B = 8, S = 512, D = 1024, DI = 768, NI = 197, NIP = 224, V = 32000;
  const int M = B * S;          // 4096
  const int MI = B * NI;        // 1576

  char* ws = (char*)d_ws;
  size_t off = 0;
  auto alloc = [&](size_t bytes) -> char* {
    char* p = ws + off; off += (bytes + 255) & ~(size_t)255; return p;
  };
  // NOTE: Wq1t/Wk1t/Wv1t contiguous (each 2MB, 256-aligned) -> fused QKV B-matrix [3072][1024].
  //       Wk2t/Wv2t contiguous (each 1.5MB) -> fused KV2 B-matrix [2048][768].
  bf16* Wq1t = (bf16*)alloc((size_t)D*D*2);
  bf16* Wk1t = (bf16*)alloc((size_t)D*D*2);
  bf16* Wv1t = (bf16*)alloc((size_t)D*D*2);
  bf16* Wq2t = (bf16*)alloc((size_t)D*D*2);
  bf16* Wk2t = (bf16*)alloc((size_t)D*DI*2);
  bf16* Wv2t = (bf16*)alloc((size_t)D*DI*2);
  bf16* Wpt  = (bf16*)alloc((size_t)V*D*2);
  float* bqkv= (float*)alloc((size_t)3*D*4);
  float* bkv2= (float*)alloc((size_t)2*D*4);
  float* xf  = (float*)alloc((size_t)M*D*4);
  bf16*  xb  = (bf16*) alloc((size_t)M*D*2);
  bf16*  imgb= (bf16*) alloc((size_t)MI*DI*2);
  bf16*  QKV = (bf16*) alloc((size_t)M*3*D*2);   // [M][3072]: Q | K | V
  bf16*  Vt  = (bf16*) alloc((size_t)M*D*2);
  float* sc1 = (float*)alloc((size_t)B*S*S*4);
  bf16*  P1  = (bf16*) alloc((size_t)B*S*S*2);
  float* ao1 = (float*)alloc((size_t)M*D*4);
  float* x2f = (float*)alloc((size_t)M*D*4);
  bf16*  x2b = (bf16*) alloc((size_t)M*D*2);
  bf16*  Q2  = (bf16*) alloc((size_t)M*D*2);
  bf16*  KV2 = (bf16*) alloc((size_t)MI*2*D*2);  // [MI][2048]: K2 | V2
  bf16*  V2t = (bf16*) alloc((size_t)B*D*NIP*2);
  float* sc2 = (float*)alloc((size_t)B*S*NIP*4);
  bf16*  P2  = (bf16*) alloc((size_t)B*S*NIP*2);
  float* ao2 = (float*)alloc((size_t)M*D*4);
  bf16*  x3b = (bf16*) alloc((size_t)M*D*2);
  (void)ws_size; (void)in_sizes; (void)n_in; (void)out_size;

  // --- weight prep (f32 [K,N] -> bf16 [N,K]) ---
  wprep4_kernel<<<dim3(D/32,  D/32, 4), 256, 0, stream>>>(Wq1, Wk1, Wv1, Wq2, Wq1t, Wk1t, Wv1t, Wq2t, D, D);
  wprep4_kernel<<<dim3(DI/32, D/32, 2), 256, 0, stream>>>(Wk2, Wv2, nullptr, nullptr, Wk2t, Wv2t, nullptr, nullptr, DI, D);
  wprep4_kernel<<<dim3(D/32,  V/32, 1), 256, 0, stream>>>(Wp, nullptr, nullptr, nullptr, Wpt, nullptr, nullptr, nullptr, D, V);
  concat_bias_kernel<<<(3*D+255)/256, 256, 0, stream>>>(bq1, bk1, bv1, D, D, D, bqkv);
  concat_bias_kernel<<<(2*D+255)/256, 256, 0, stream>>>(bk2, bv2, nullptr, D, D, 0, bkv2);

  // --- embed + img convert ---
  embed_kernel<<<M, 256, 0, stream>>>(tokens, emb, xf, xb);
  {
    long n = (long)MI * DI;
    cvt_bf16_kernel<<<(int)((n + 255)/256), 256, 0, stream>>>(img, imgb, n);
  }

  auto gemmF = [&](const bf16* A, const bf16* Bt, float* C, const float* bias,
                   int m, int n, int k, int lda, int ldb, int ldc,
                   long sA, long sB, long sC, int batch) {
    dim3 g((m+127)/128, (n+127)/128, batch);
    gemm_bt_kernel<float><<<g, 256, 0, stream>>>(A, Bt, C, bias, m, n, k, lda, ldb, ldc, sA, sB, sC);
  };
  auto gemmB = [&](const bf16* A, const bf16* Bt, bf16* C, const float* bias,
                   int m, int n, int k, int lda, int ldb, int ldc,
                   long sA, long sB, long sC, int batch) {
    dim3 g((m+127)/128, (n+127)/128, batch);
    gemm_bt_kernel<bf16><<<g, 256, 0, stream>>>(A, Bt, C, bias, m, n, k, lda, ldb, ldc, sA, sB, sC);
  };

  // --- block 1: causal self-attention (fused QKV GEMM: N=3072) ---
  gemmB(xb, Wq1t, QKV, bqkv, M, 3*D, D, D, D, 3*D, 0, 0, 0, 1);
  transpose_pad_kernel<<<dim3(S/32, D/32, B), 256, 0, stream>>>(
      QKV + 2*D, Vt, S, D, 3*D, S, (long)S*3*D, (long)D*S);
  gemmF(QKV, QKV + D, sc1, nullptr, S, S, D, 3*D, 3*D, S, (long)S*3*D, (long)S*3*D, (long)S*S, B);
  softmax_causal_kernel<<<M, 64, 0, stream>>>(sc1, P1);
  gemmF(P1, Vt, ao1, nullptr, S, D, S, S, S, D, (long)S*S, (long)D*S, (long)S*D, B);
  add_ln_kernel<<<M, 256, 0, stream>>>(ao1, xf, g1, b1, x2f, x2b);

  // --- block 2: cross-attention over image tokens (fused K2V2 GEMM: N=2048) ---
  gemmB(x2b, Wq2t, Q2, bq2, M, D, D, D, D, D, 0, 0, 0, 1);
  gemmB(imgb, Wk2t, KV2, bkv2, MI, 2*D, DI, DI, DI, 2*D, 0, 0, 0, 1);
  transpose_pad_kernel<<<dim3((NIP+31)/32, D/32, B), 256, 0, stream>>>(
      KV2 + D, V2t, NI, D, 2*D, NIP, (long)NI*2*D, (long)D*NIP);
  gemmF(Q2, KV2, sc2, nullptr, S, NI, D, D, 2*D, NIP, (long)S*D, (long)NI*2*D, (long)S*NIP, B);
  softmax_cross_kernel<<<M, 64, 0, stream>>>(sc2, P2);
  gemmF(P2, V2t, ao2, nullptr, S, D, NIP, NIP, NIP, D, (long)S*NIP, (long)D*NIP, (long)S*D, B);
  add_ln_kernel<<<M, 256, 0, stream>>>(ao2, x2f, g2, b2, nullptr, x3b);

  // --- vocab projection: m97-structure 128x128 kernel (grid 32x250 = 8000 blocks) ---
  {
    dim3 g((M/128) * (V/128));
    gemm_vocab_kernel<<<g, 256, 0, stream>>>(x3b, Wpt, out, bp, M, V, D, D, D, V);
  }
}

// Round 7
// 734.055 us; speedup vs baseline: 3.6618x; 1.1282x over previous
//
#include <hip/hip_runtime.h>
#include <hip/hip_bf16.h>

// Decoder forward: embed+posenc -> causal self-attn -> LN -> cross-attn(img) -> LN -> vocab proj
// B=8 S=512 D=1024 DI=768 NI=197(pad 224) V=32000. GEMMs bf16 MFMA (16x16x32), f32 accum.
// R7: vocab GEMM reverted to R2 ring-4 (best measured: 367us); QKV routed through it;
//     nontemporal f32 C-stores; embed powf->exp2f. R6's 128^2 experiment removed.

#define DEV __device__ __forceinline__

typedef __bf16 bf16x8 __attribute__((ext_vector_type(8)));
typedef float f32x4 __attribute__((ext_vector_type(4)));
typedef unsigned int u32;
typedef __hip_bfloat16 bf16;

DEV void llds16(const void* g, void* l) {
  __builtin_amdgcn_global_load_lds((const __attribute__((address_space(1))) u32*)g,
                                   (__attribute__((address_space(3))) u32*)l, 16, 0, 0);
}

DEV float wredsum(float v){
#pragma unroll
  for (int o = 32; o; o >>= 1) v += __shfl_xor(v, o, 64);
  return v;
}
DEV float wredmax(float v){
#pragma unroll
  for (int o = 32; o; o >>= 1) v = fmaxf(v, __shfl_xor(v, o, 64));
  return v;
}

DEV void store_out(float* p, float v){ *p = v; }
DEV void store_out(bf16* p, float v){ *p = __float2bfloat16(v); }

// ================= big GEMM: C[M,N] = A[M,K] @ Bt[N,K]^T + bias =================
// R2 structure (best measured for vocab): 256x256 tile, BK=32, 8 waves (2Mx4N),
// per-wave 128x64 = 8x4 frags of 16x16x32. LDS: 4-slot ring x (A 16KB + B 16KB)
// = 128 KiB. Stage tile t+3 during tile t; counted vmcnt(8) at tile boundary.
// T2 swizzle (pre-swizzled global source + swizzled ds_read): 0 bank conflicts (R2-verified).
// T1 XCD-bijective block swizzle; T5 setprio around MFMA clusters.
// Requires: M%256==0, N%256==0, K%32==0, K>=96.
template<typename OutT>
__global__ __launch_bounds__(512, 1) void gemm256_kernel(
    const bf16* __restrict__ A, const bf16* __restrict__ Bt, OutT* __restrict__ C,
    const float* __restrict__ bias, int M, int N, int K, int lda, int ldb, int ldc)
{
  __shared__ alignas(16) char lds[131072];
  const int tid  = threadIdx.x;
  const int wave = tid >> 6, lane = tid & 63;
  const int lo = lane & 15, hi = lane >> 4;
  const int hi2 = hi ^ ((lo >> 1) & 3);            // swizzled 16B slot for ds_read
  const int wr = wave >> 2, wc = wave & 3;
  const int koff = (((lane & 3) ^ ((lane >> 3) & 3)) << 3);  // pre-swizzled global k (write side)

  const int nbx = M >> 8;
  const int nwg = nbx * (N >> 8);
  int id = blockIdx.x;
  int g = (nwg & 7) ? id : ((id & 7) * (nwg >> 3) + (id >> 3));
  const int row0 = (g % nbx) * 256, col0 = (g / nbx) * 256;
  const int NT = K >> 5;
  const int srow = lane >> 2;

  auto stageA = [&](int t) {
    char* base = lds + (t & 3) * 32768;
    const int kk = (t << 5) + koff;
#pragma unroll
    for (int j = 0; j < 2; j++) {
      const int seg = j * 8 + wave;
      llds16(A + (long)(row0 + seg * 16 + srow) * lda + kk, base + seg * 1024);
    }
  };
  auto stageB = [&](int t) {
    char* base = lds + (t & 3) * 32768 + 16384;
    const int kk = (t << 5) + koff;
#pragma unroll
    for (int j = 0; j < 2; j++) {
      const int seg = j * 8 + wave;
      llds16(Bt + (long)(col0 + seg * 16 + srow) * ldb + kk, base + seg * 1024);
    }
  };

  f32x4 acc[8][4] = {};

  // prologue: stage tiles 0,1,2 (12 loads/thread); drain tile 0's 4.
  stageA(0); stageB(0);
  stageA(1); stageB(1);
  stageA(2); stageB(2);
  asm volatile("s_waitcnt vmcnt(8)" ::: "memory");
  __builtin_amdgcn_s_barrier();
  asm volatile("" ::: "memory");

  for (int t = 0; t < NT; t++) {
    char* As = lds + (t & 3) * 32768;
    char* Bs = As + 16384;
    bf16x8 af[4], bfv[4];
    // ---- phase 1: frags A0-3 + B0-3, stage A(t+3), MFMA quadrant 0 ----
#pragma unroll
    for (int m = 0; m < 4; m++)
      af[m] = *(const bf16x8*)(As + ((wr * 128 + m * 16 + lo) << 6) + (hi2 << 4));
#pragma unroll
    for (int n = 0; n < 4; n++)
      bfv[n] = *(const bf16x8*)(Bs + ((wc * 64 + n * 16 + lo) << 6) + (hi2 << 4));
    if (t + 3 < NT) stageA(t + 3);
    __builtin_amdgcn_s_setprio(1);
#pragma unroll
    for (int m = 0; m < 4; m++)
#pragma unroll
      for (int n = 0; n < 4; n++)
        acc[m][n] = __builtin_amdgcn_mfma_f32_16x16x32_bf16(af[m], bfv[n], acc[m][n], 0, 0, 0);
    __builtin_amdgcn_s_setprio(0);
    asm volatile("" ::: "memory");
    __builtin_amdgcn_s_barrier();
    asm volatile("" ::: "memory");
    // ---- phase 2: frags A4-7, stage B(t+3), MFMA quadrant 1 ----
#pragma unroll
    for (int m = 0; m < 4; m++)
      af[m] = *(const bf16x8*)(As + ((wr * 128 + (m + 4) * 16 + lo) << 6) + (hi2 << 4));
    if (t + 3 < NT) stageB(t + 3);
    __builtin_amdgcn_s_setprio(1);
#pragma unroll
    for (int m = 0; m < 4; m++)
#pragma unroll
      for (int n = 0; n < 4; n++)
        acc[m + 4][n] = __builtin_amdgcn_mfma_f32_16x16x32_bf16(af[m], bfv[n], acc[m + 4][n], 0, 0, 0);
    __builtin_amdgcn_s_setprio(0);
    // ---- tile boundary: counted drain of tile t+1's stages, then barrier ----
    if (t < NT - 3)       asm volatile("s_waitcnt vmcnt(8)" ::: "memory");
    else if (t == NT - 3) asm volatile("s_waitcnt vmcnt(4)" ::: "memory");
    else                  asm volatile("s_waitcnt vmcnt(0)" ::: "memory");
    __builtin_amdgcn_s_barrier();
    asm volatile("" ::: "memory");
  }

#pragma unroll
  for (int m = 0; m < 8; m++) {
    const int r = row0 + wr * 128 + m * 16 + hi * 4;
#pragma unroll
    for (int n = 0; n < 4; n++) {
      const int c = col0 + wc * 64 + n * 16 + lo;
      const float bb = bias ? bias[c] : 0.0f;
#pragma unroll
      for (int j = 0; j < 4; j++) {
        const float v = acc[m][n][j] + bb;
        if constexpr (__is_same(OutT, float)) {
          __builtin_nontemporal_store(v, &C[(long)(r + j) * ldc + c]);  // don't evict B-panels
        } else {
          C[(long)(r + j) * ldc + c] = __float2bfloat16(v);
        }
      }
    }
  }
}

// ---------------- GEMM: C[M,N] = A[M,K] @ Bt[N,K]^T (+bias[N]) ----------------
// 128x128 tile, BK=32, 4 waves (2x2), T2-swizzled, bounds-guarded (general shapes).
template<typename OutT>
__global__ __launch_bounds__(256) void gemm_bt_kernel(
    const bf16* __restrict__ A, const bf16* __restrict__ Bt, OutT* __restrict__ C,
    const float* __restrict__ bias, int M, int N, int K,
    int lda, int ldb, int ldc, long sA, long sB, long sC)
{
  A  += (long)blockIdx.z * sA;
  Bt += (long)blockIdx.z * sB;
  C  += (long)blockIdx.z * sC;
  __shared__ alignas(16) bf16 As[128*32];
  __shared__ alignas(16) bf16 Bs[128*32];
  const int tid = threadIdx.x;
  const int wave = tid >> 6, lane = tid & 63;
  const int lo = lane & 15, hi = lane >> 4;
  const int hi2 = hi ^ ((lo >> 1) & 3);
  const int wr = wave >> 1, wc = wave & 1;
  const int row0 = blockIdx.x * 128, col0 = blockIdx.y * 128;
  const int srow  = lane >> 2;
  const int skoff = (((lane & 3) ^ ((lane >> 3) & 3)) << 3);

  f32x4 acc[4][4] = {};

  for (int k0 = 0; k0 < K; k0 += 32) {
#pragma unroll
    for (int c = 0; c < 2; ++c) {
      const int seg = c*4 + wave;
      int ra = row0 + seg*16 + srow; ra = ra < M ? ra : M-1;
      llds16(A + (long)ra*lda + (k0 + skoff), (char*)As + seg*1024);
      int rb = col0 + seg*16 + srow; rb = rb < N ? rb : N-1;
      llds16(Bt + (long)rb*ldb + (k0 + skoff), (char*)Bs + seg*1024);
    }
    __syncthreads();
    bf16x8 af[4], bfv[4];
#pragma unroll
    for (int m = 0; m < 4; m++)
      af[m] = *(const bf16x8*)((const char*)As + (wr*64 + m*16 + lo)*64 + hi2*16);
#pragma unroll
    for (int n = 0; n < 4; n++)
      bfv[n] = *(const bf16x8*)((const char*)Bs + (wc*64 + n*16 + lo)*64 + hi2*16);
#pragma unroll
    for (int m = 0; m < 4; m++)
#pragma unroll
      for (int n = 0; n < 4; n++)
        acc[m][n] = __builtin_amdgcn_mfma_f32_16x16x32_bf16(af[m], bfv[n], acc[m][n], 0, 0, 0);
    __syncthreads();
  }

#pragma unroll
  for (int m = 0; m < 4; m++) {
    const int rbase = row0 + wr*64 + m*16 + hi*4;
#pragma unroll
    for (int n = 0; n < 4; n++) {
      const int cc = col0 + wc*64 + n*16 + lo;
      if (cc >= N) continue;
      const float bb = bias ? bias[cc] : 0.0f;
#pragma unroll
      for (int j = 0; j < 4; j++) {
        const int rr = rbase + j;
        if (rr < M) store_out(&C[(long)rr*ldc + cc], acc[m][n][j] + bb);
      }
    }
  }
}

// ---------------- weight prep: W[K,N] f32 -> Wt[N,K] bf16, z-indexed up to 4 pairs ----------------
__global__ __launch_bounds__(256) void wprep4_kernel(
    const float* W0, const float* W1, const float* W2, const float* W3,
    bf16* T0, bf16* T1, bf16* T2, bf16* T3, int K, int N)
{
  const int z = blockIdx.z;
  const float* W = z == 0 ? W0 : z == 1 ? W1 : z == 2 ? W2 : W3;
  bf16* T = z == 0 ? T0 : z == 1 ? T1 : z == 2 ? T2 : T3;
  __shared__ bf16 t[32][33];
  const int k0 = blockIdx.x * 32, n0 = blockIdx.y * 32;
  const int tx = threadIdx.x & 31, ty = threadIdx.x >> 5;
#pragma unroll
  for (int i = 0; i < 4; i++)
    t[ty + i*8][tx] = __float2bfloat16(W[(long)(k0 + ty + i*8)*N + n0 + tx]);
  __syncthreads();
#pragma unroll
  for (int i = 0; i < 4; i++)
    T[(long)(n0 + ty + i*8)*K + k0 + tx] = t[tx][ty + i*8];
}

// ---------------- bf16 transpose with zero-pad: in[R x Cc (ld inLD)] -> out[Cc x outLD] ----------------
__global__ __launch_bounds__(256) void transpose_pad_kernel(
    const bf16* __restrict__ in, bf16* __restrict__ out,
    int R, int Cc, int inLD, int outLD, long inBatch, long outBatch)
{
  in  += (long)blockIdx.z * inBatch;
  out += (long)blockIdx.z * outBatch;
  __shared__ bf16 t[32][33];
  const int r0 = blockIdx.x * 32, c0 = blockIdx.y * 32;
  const int tx = threadIdx.x & 31, ty = threadIdx.x >> 5;
#pragma unroll
  for (int i = 0; i < 4; i++) {
    const int r = r0 + ty + i*8;
    bf16 v = __float2bfloat16(0.0f);
    if (r < R) v = in[(long)r*inLD + c0 + tx];
    t[ty + i*8][tx] = v;
  }
  __syncthreads();
#pragma unroll
  for (int i = 0; i < 4; i++) {
    const int oc = r0 + tx;
    const int orow = c0 + ty + i*8;
    if (oc < outLD) out[(long)orow*outLD + oc] = t[tx][ty + i*8];
  }
}

// ---------------- bias concat (up to 3) ----------------
__global__ __launch_bounds__(256) void concat_bias_kernel(
    const float* a, const float* b, const float* c, int n1, int n2, int n3, float* out)
{
  const int i = blockIdx.x * 256 + threadIdx.x;
  if (i >= n1 + n2 + n3) return;
  out[i] = i < n1 ? a[i] : (i < n1 + n2 ? b[i - n1] : c[i - n1 - n2]);
}

// ---------------- embedding + sinusoidal positional encoding ----------------
__global__ __launch_bounds__(256) void embed_kernel(
    const int* __restrict__ tok, const float* __restrict__ tbl,
    float* __restrict__ xf, bf16* __restrict__ xb)
{
  const int row = blockIdx.x;
  const int s = row & 511;
  const float pos = (float)s;
  const float* te = tbl + (long)tok[row] * 1024;
  const int d0 = threadIdx.x * 4;
  float4 v = *(const float4*)(te + d0);
  float o[4] = {v.x, v.y, v.z, v.w};
  // 10000^(-i2/1024) = exp2(-i2 * log2(10000)/1024); log2(10000)=13.287712379549449
#pragma unroll
  for (int k = 0; k < 4; k++) {
    const int d = d0 + k;
    const int i2 = d & ~1;
    const float ang = pos * exp2f((float)i2 * -0.0129762816f);
    o[k] += (d & 1) ? __cosf(ang) : __sinf(ang);
  }
  *(float4*)(xf + (long)row*1024 + d0) = make_float4(o[0], o[1], o[2], o[3]);
#pragma unroll
  for (int k = 0; k < 4; k++) xb[(long)row*1024 + d0 + k] = __float2bfloat16(o[k]);
}

// ---------------- f32 -> bf16 copy ----------------
__global__ __launch_bounds__(256) void cvt_bf16_kernel(const float* __restrict__ in, bf16* __restrict__ out, long n)
{
  long i = (long)blockIdx.x * blockDim.x + threadIdx.x;
  if (i < n) out[i] = __float2bfloat16(in[i]);
}

// ---------------- causal softmax over scores [B*S rows][512] ----------------
__global__ __launch_bounds__(64) void softmax_causal_kernel(
    const float* __restrict__ Sc, bf16* __restrict__ P)
{
  const int row = blockIdx.x;
  const int q = row & 511;
  const float* srow = Sc + (long)row * 512;
  bf16* prow = P + (long)row * 512;
  const int lane = threadIdx.x;
  const float scale = 0.03125f;
  float mx = -1e30f;
  for (int j = lane; j <= q; j += 64) mx = fmaxf(mx, srow[j]);
  mx = wredmax(mx);
  float sum = 0.0f;
  for (int j = lane; j <= q; j += 64) sum += expf((srow[j] - mx) * scale);
  sum = wredsum(sum);
  const float inv = 1.0f / sum;
  for (int j = lane; j < 512; j += 64) {
    float p = (j <= q) ? expf((srow[j] - mx) * scale) * inv : 0.0f;
    prow[j] = __float2bfloat16(p);
  }
}

// ---------------- cross softmax: rows of 197 valid (ld 224) ----------------
__global__ __launch_bounds__(64) void softmax_cross_kernel(
    const float* __restrict__ Sc, bf16* __restrict__ P)
{
  const int row = blockIdx.x;
  const float* srow = Sc + (long)row * 224;
  bf16* prow = P + (long)row * 224;
  const int lane = threadIdx.x;
  const float scale = 0.03125f;
  float mx = -1e30f;
  for (int j = lane; j < 197; j += 64) mx = fmaxf(mx, srow[j]);
  mx = wredmax(mx);
  float sum = 0.0f;
  for (int j = lane; j < 197; j += 64) sum += expf((srow[j] - mx) * scale);
  sum = wredsum(sum);
  const float inv = 1.0f / sum;
  for (int j = lane; j < 224; j += 64) {
    float p = (j < 197) ? expf((srow[j] - mx) * scale) * inv : 0.0f;
    prow[j] = __float2bfloat16(p);
  }
}

// ---------------- add residual + LayerNorm; write f32 (optional) + bf16 ----------------
__global__ __launch_bounds__(256) void add_ln_kernel(
    const float* __restrict__ Acc, const float* __restrict__ Res,
    const float* __restrict__ g, const float* __restrict__ b,
    float* __restrict__ outf, bf16* __restrict__ outb)
{
  const int row = blockIdx.x;
  const float* a = Acc + (long)row * 1024;
  const float* r = Res + (long)row * 1024;
  float vals[4], s = 0.0f, ss = 0.0f;
#pragma unroll
  for (int i = 0; i < 4; i++) {
    const int d = threadIdx.x + i*256;
    const float v = a[d] + r[d];
    vals[i] = v; s += v; ss += v*v;
  }
  s = wredsum(s); ss = wredsum(ss);
  __shared__ float sh[8];
  const int wave = threadIdx.x >> 6, lane = threadIdx.x & 63;
  if (lane == 0) { sh[wave] = s; sh[wave+4] = ss; }
  __syncthreads();
  s  = sh[0] + sh[1] + sh[2] + sh[3];
  ss = sh[4] + sh[5] + sh[6] + sh[7];
  const float mean = s * (1.0f/1024.0f);
  const float var  = ss * (1.0f/1024.0f) - mean*mean;
  const float inv  = rsqrtf(var + 1e-5f);
#pragma unroll
  for (int i = 0; i < 4; i++) {
    const int d = threadIdx.x + i*256;
    const float y = (vals[i] - mean) * inv * g[d] + b[d];
    if (outf) outf[(long)row*1024 + d] = y;
    outb[(long)row*1024 + d] = __float2bfloat16(y);
  }
}

// =======================================================================================
extern "C" void kernel_launch(void* const* d_in, const int* in_sizes, int n_in,
                              void* d_out, int out_size, void* d_ws, size_t ws_size,
                              hipStream_t stream) {
  const int*   tokens = (const int*)  d_in[0];
  const float* img    = (const float*)d_in[1];
  const float* emb    = (const float*)d_in[2];
  const float* Wq1    = (const float*)d_in[3];
  const float* bq1    = (const float*)d_in[4];
  const float* Wk1    = (const float*)d_in[5];
  const float* bk1    = (const float*)d_in[6];
  const float* Wv1    = (const float*)d_in[7];
  const float* bv1    = (const float*)d_in[8];
  const float* g1     = (const float*)d_in[9];
  const float* b1     = (const float*)d_in[10];
  const float* Wq2    = (const float*)d_in[11];
  const float* bq2    = (const float*)d_in[12];
  const float* Wk2    = (const float*)d_in[13];
  const float* bk2    = (const float*)d_in[14];
  const float* Wv2    = (const float*)d_in[15];
  const float* bv2    = (const float*)d_in[16];
  const float* g2     = (const float*)d_in[17];
  const float* b2     = (const float*)d_in[18];
  const float* Wp     = (const float*)d_in[19];
  const float* bp     = (const float*)d_in[20];
  float* out = (float*)d_out;

  const int B = 8, S = 512, D = 1024, DI = 768, NI = 197, NIP = 224, V = 32000;
  const int M = B * S;          // 4096
  const int MI = B * NI;        // 1576

  char* ws = (char*)d_ws;
  size_t off = 0;
  auto alloc = [&](size_t bytes) -> char* {
    char* p = ws + off; off += (bytes + 255) & ~(size_t)255; return p;
  };
  // NOTE: Wq1t/Wk1t/Wv1t contiguous (each 2MB, 256-aligned) -> fused QKV B-matrix [3072][1024].
  //       Wk2t/Wv2t contiguous (each 1.5MB) -> fused KV2 B-matrix [2048][768].
  bf16* Wq1t = (bf16*)alloc((size_t)D*D*2);
  bf16* Wk1t = (bf16*)alloc((size_t)D*D*2);
  bf16* Wv1t = (bf16*)alloc((size_t)D*D*2);
  bf16* Wq2t = (bf16*)alloc((size_t)D*D*2);
  bf16* Wk2t = (bf16*)alloc((size_t)D*DI*2);
  bf16* Wv2t = (bf16*)alloc((size_t)D*DI*2);
  bf16* Wpt  = (bf16*)alloc((size_t)V*D*2);
  float* bqkv= (float*)alloc((size_t)3*D*4);
  float* bkv2= (float*)alloc((size_t)2*D*4);
  float* xf  = (float*)alloc((size_t)M*D*4);
  bf16*  xb  = (bf16*) alloc((size_t)M*D*2);
  bf16*  imgb= (bf16*) alloc((size_t)MI*DI*2);
  bf16*  QKV = (bf16*) alloc((size_t)M*3*D*2);   // [M][3072]: Q | K | V
  bf16*  Vt  = (bf16*) alloc((size_t)M*D*2);
  float* sc1 = (float*)alloc((size_t)B*S*S*4);
  bf16*  P1  = (bf16*) alloc((size_t)B*S*S*2);
  float* ao1 = (float*)alloc((size_t)M*D*4);
  float* x2f = (float*)alloc((size_t)M*D*4);
  bf16*  x2b = (bf16*) alloc((size_t)M*D*2);
  bf16*  Q2  = (bf16*) alloc((size_t)M*D*2);
  bf16*  KV2 = (bf16*) alloc((size_t)MI*2*D*2);  // [MI][2048]: K2 | V2
  bf16*  V2t = (bf16*) alloc((size_t)B*D*NIP*2);
  float* sc2 = (float*)alloc((size_t)B*S*NIP*4);
  bf16*  P2  = (bf16*) alloc((size_t)B*S*NIP*2);
  float* ao2 = (float*)alloc((size_t)M*D*4);
  bf16*  x3b = (bf16*) alloc((size_t)M*D*2);
  (void)ws_size; (void)in_sizes; (void)n_in; (void)out_size;

  // --- weight prep (f32 [K,N] -> bf16 [N,K]) ---
  wprep4_kernel<<<dim3(D/32,  D/32, 4), 256, 0, stream>>>(Wq1, Wk1, Wv1, Wq2, Wq1t, Wk1t, Wv1t, Wq2t, D, D);
  wprep4_kernel<<<dim3(DI/32, D/32, 2), 256, 0, stream>>>(Wk2, Wv2, nullptr, nullptr, Wk2t, Wv2t, nullptr, nullptr, DI, D);
  wprep4_kernel<<<dim3(D/32,  V/32, 1), 256, 0, stream>>>(Wp, nullptr, nullptr, nullptr, Wpt, nullptr, nullptr, nullptr, D, V);
  concat_bias_kernel<<<(3*D+255)/256, 256, 0, stream>>>(bq1, bk1, bv1, D, D, D, bqkv);
  concat_bias_kernel<<<(2*D+255)/256, 256, 0, stream>>>(bk2, bv2, nullptr, D, D, 0, bkv2);

  // --- embed + img convert ---
  embed_kernel<<<M, 256, 0, stream>>>(tokens, emb, xf, xb);
  {
    long n = (long)MI * DI;
    cvt_bf16_kernel<<<(int)((n + 255)/256), 256, 0, stream>>>(img, imgb, n);
  }

  auto gemmF = [&](const bf16* A, const bf16* Bt, float* C, const float* bias,
                   int m, int n, int k, int lda, int ldb, int ldc,
                   long sA, long sB, long sC, int batch) {
    dim3 g((m+127)/128, (n+127)/128, batch);
    gemm_bt_kernel<float><<<g, 256, 0, stream>>>(A, Bt, C, bias, m, n, k, lda, ldb, ldc, sA, sB, sC);
  };
  auto gemmB = [&](const bf16* A, const bf16* Bt, bf16* C, const float* bias,
                   int m, int n, int k, int lda, int ldb, int ldc,
                   long sA, long sB, long sC, int batch) {
    dim3 g((m+127)/128, (n+127)/128, batch);
    gemm_bt_kernel<bf16><<<g, 256, 0, stream>>>(A, Bt, C, bias, m, n, k, lda, ldb, ldc, sA, sB, sC);
  };

  // --- block 1: causal self-attention (fused QKV GEMM via 256^2 kernel: grid 16x12=192) ---
  gemm256_kernel<bf16><<<dim3((M/256)*(3*D/256)), 512, 0, stream>>>(
      xb, Wq1t, QKV, bqkv, M, 3*D, D, D, D, 3*D);
  transpose_pad_kernel<<<dim3(S/32, D/32, B), 256, 0, stream>>>(
      QKV + 2*D, Vt, S, D, 3*D, S, (long)S*3*D, (long)D*S);
  gemmF(QKV, QKV + D, sc1, nullptr, S, S, D, 3*D, 3*D, S, (long)S*3*D, (long)S*3*D, (long)S*S, B);
  softmax_causal_kernel<<<M, 64, 0, stream>>>(sc1, P1);
  gemmF(P1, Vt, ao1, nullptr, S, D, S, S, S, D, (long)S*S, (long)D*S, (long)S*D, B);
  add_ln_kernel<<<M, 256, 0, stream>>>(ao1, xf, g1, b1, x2f, x2b);

  // --- block 2: cross-attention over image tokens (fused K2V2 GEMM: N=2048) ---
  gemmB(x2b, Wq2t, Q2, bq2, M, D, D, D, D, D, 0, 0, 0, 1);
  gemmB(imgb, Wk2t, KV2, bkv2, MI, 2*D, DI, DI, DI, 2*D, 0, 0, 0, 1);
  transpose_pad_kernel<<<dim3((NIP+31)/32, D/32, B), 256, 0, stream>>>(
      KV2 + D, V2t, NI, D, 2*D, NIP, (long)NI*2*D, (long)D*NIP);
  gemmF(Q2, KV2, sc2, nullptr, S, NI, D, D, 2*D, NIP, (long)S*D, (long)NI*2*D, (long)S*NIP, B);
  softmax_cross_kernel<<<M, 64, 0, stream>>>(sc2, P2);
  gemmF(P2, V2t, ao2, nullptr, S, D, NIP, NIP, NIP, D, (long)S*NIP, (long)D*NIP, (long)S*D, B);
  add_ln_kernel<<<M, 256, 0, stream>>>(ao2, x2f, g2, b2, nullptr, x3b);

  // --- vocab projection: R2 ring-4 256^2 kernel (grid 16x125 = 2000 blocks) ---
  gemm256_kernel<float><<<dim3((M/256)*(V/256)), 512, 0, stream>>>(
      x3b, Wpt, out, bp, M, V, D, D, D, V);
}

// Round 8
// 695.342 us; speedup vs baseline: 3.8657x; 1.0557x over previous
//
#include <hip/hip_runtime.h>
#include <hip/hip_bf16.h>

// Decoder forward: embed+posenc -> causal self-attn -> LN -> cross-attn(img) -> LN -> vocab proj
// B=8 S=512 D=1024 DI=768 NI=197(pad 224) V=32000. GEMMs bf16 MFMA (16x16x32), f32 accum.
// R8: revert R7's nontemporal C-store (write amplification 512->715MB, vocab 367->435us).
//     Vocab GEMM = R2 ring-4 256^2 with plain cached stores; QKV stays on gemm256<bf16>.

#define DEV __device__ __forceinline__

typedef __bf16 bf16x8 __attribute__((ext_vector_type(8)));
typedef float f32x4 __attribute__((ext_vector_type(4)));
typedef unsigned int u32;
typedef __hip_bfloat16 bf16;

DEV void llds16(const void* g, void* l) {
  __builtin_amdgcn_global_load_lds((const __attribute__((address_space(1))) u32*)g,
                                   (__attribute__((address_space(3))) u32*)l, 16, 0, 0);
}

DEV float wredsum(float v){
#pragma unroll
  for (int o = 32; o; o >>= 1) v += __shfl_xor(v, o, 64);
  return v;
}
DEV float wredmax(float v){
#pragma unroll
  for (int o = 32; o; o >>= 1) v = fmaxf(v, __shfl_xor(v, o, 64));
  return v;
}

DEV void store_out(float* p, float v){ *p = v; }
DEV void store_out(bf16* p, float v){ *p = __float2bfloat16(v); }

// ================= big GEMM: C[M,N] = A[M,K] @ Bt[N,K]^T + bias =================
// R2 structure (best measured for vocab: 367us): 256x256 tile, BK=32, 8 waves (2Mx4N),
// per-wave 128x64 = 8x4 frags of 16x16x32. LDS: 4-slot ring x (A 16KB + B 16KB)
// = 128 KiB. Stage tile t+3 during tile t; counted vmcnt(8) at tile boundary.
// T2 swizzle (pre-swizzled global source + swizzled ds_read): 0 bank conflicts.
// T1 XCD-bijective block swizzle; T5 setprio around MFMA clusters.
// Requires: M%256==0, N%256==0, K%32==0, K>=96.
template<typename OutT>
__global__ __launch_bounds__(512, 1) void gemm256_kernel(
    const bf16* __restrict__ A, const bf16* __restrict__ Bt, OutT* __restrict__ C,
    const float* __restrict__ bias, int M, int N, int K, int lda, int ldb, int ldc)
{
  __shared__ alignas(16) char lds[131072];
  const int tid  = threadIdx.x;
  const int wave = tid >> 6, lane = tid & 63;
  const int lo = lane & 15, hi = lane >> 4;
  const int hi2 = hi ^ ((lo >> 1) & 3);            // swizzled 16B slot for ds_read
  const int wr = wave >> 2, wc = wave & 3;
  const int koff = (((lane & 3) ^ ((lane >> 3) & 3)) << 3);  // pre-swizzled global k (write side)

  const int nbx = M >> 8;
  const int nwg = nbx * (N >> 8);
  int id = blockIdx.x;
  int g = (nwg & 7) ? id : ((id & 7) * (nwg >> 3) + (id >> 3));
  const int row0 = (g % nbx) * 256, col0 = (g / nbx) * 256;
  const int NT = K >> 5;
  const int srow = lane >> 2;

  auto stageA = [&](int t) {
    char* base = lds + (t & 3) * 32768;
    const int kk = (t << 5) + koff;
#pragma unroll
    for (int j = 0; j < 2; j++) {
      const int seg = j * 8 + wave;
      llds16(A + (long)(row0 + seg * 16 + srow) * lda + kk, base + seg * 1024);
    }
  };
  auto stageB = [&](int t) {
    char* base = lds + (t & 3) * 32768 + 16384;
    const int kk = (t << 5) + koff;
#pragma unroll
    for (int j = 0; j < 2; j++) {
      const int seg = j * 8 + wave;
      llds16(Bt + (long)(col0 + seg * 16 + srow) * ldb + kk, base + seg * 1024);
    }
  };

  f32x4 acc[8][4] = {};

  // prologue: stage tiles 0,1,2 (12 loads/thread); drain tile 0's 4.
  stageA(0); stageB(0);
  stageA(1); stageB(1);
  stageA(2); stageB(2);
  asm volatile("s_waitcnt vmcnt(8)" ::: "memory");
  __builtin_amdgcn_s_barrier();
  asm volatile("" ::: "memory");

  for (int t = 0; t < NT; t++) {
    char* As = lds + (t & 3) * 32768;
    char* Bs = As + 16384;
    bf16x8 af[4], bfv[4];
    // ---- phase 1: frags A0-3 + B0-3, stage A(t+3), MFMA quadrant 0 ----
#pragma unroll
    for (int m = 0; m < 4; m++)
      af[m] = *(const bf16x8*)(As + ((wr * 128 + m * 16 + lo) << 6) + (hi2 << 4));
#pragma unroll
    for (int n = 0; n < 4; n++)
      bfv[n] = *(const bf16x8*)(Bs + ((wc * 64 + n * 16 + lo) << 6) + (hi2 << 4));
    if (t + 3 < NT) stageA(t + 3);
    __builtin_amdgcn_s_setprio(1);
#pragma unroll
    for (int m = 0; m < 4; m++)
#pragma unroll
      for (int n = 0; n < 4; n++)
        acc[m][n] = __builtin_amdgcn_mfma_f32_16x16x32_bf16(af[m], bfv[n], acc[m][n], 0, 0, 0);
    __builtin_amdgcn_s_setprio(0);
    asm volatile("" ::: "memory");
    __builtin_amdgcn_s_barrier();
    asm volatile("" ::: "memory");
    // ---- phase 2: frags A4-7, stage B(t+3), MFMA quadrant 1 ----
#pragma unroll
    for (int m = 0; m < 4; m++)
      af[m] = *(const bf16x8*)(As + ((wr * 128 + (m + 4) * 16 + lo) << 6) + (hi2 << 4));
    if (t + 3 < NT) stageB(t + 3);
    __builtin_amdgcn_s_setprio(1);
#pragma unroll
    for (int m = 0; m < 4; m++)
#pragma unroll
      for (int n = 0; n < 4; n++)
        acc[m + 4][n] = __builtin_amdgcn_mfma_f32_16x16x32_bf16(af[m], bfv[n], acc[m + 4][n], 0, 0, 0);
    __builtin_amdgcn_s_setprio(0);
    // ---- tile boundary: counted drain of tile t+1's stages, then barrier ----
    if (t < NT - 3)       asm volatile("s_waitcnt vmcnt(8)" ::: "memory");
    else if (t == NT - 3) asm volatile("s_waitcnt vmcnt(4)" ::: "memory");
    else                  asm volatile("s_waitcnt vmcnt(0)" ::: "memory");
    __builtin_amdgcn_s_barrier();
    asm volatile("" ::: "memory");
  }

#pragma unroll
  for (int m = 0; m < 8; m++) {
    const int r = row0 + wr * 128 + m * 16 + hi * 4;
#pragma unroll
    for (int n = 0; n < 4; n++) {
      const int c = col0 + wc * 64 + n * 16 + lo;
      const float bb = bias ? bias[c] : 0.0f;
#pragma unroll
      for (int j = 0; j < 4; j++)
        store_out(&C[(long)(r + j) * ldc + c], acc[m][n][j] + bb);
    }
  }
}

// ---------------- GEMM: C[M,N] = A[M,K] @ Bt[N,K]^T (+bias[N]) ----------------
// 128x128 tile, BK=32, 4 waves (2x2), T2-swizzled, bounds-guarded (general shapes).
template<typename OutT>
__global__ __launch_bounds__(256) void gemm_bt_kernel(
    const bf16* __restrict__ A, const bf16* __restrict__ Bt, OutT* __restrict__ C,
    const float* __restrict__ bias, int M, int N, int K,
    int lda, int ldb, int ldc, long sA, long sB, long sC)
{
  A  += (long)blockIdx.z * sA;
  Bt += (long)blockIdx.z * sB;
  C  += (long)blockIdx.z * sC;
  __shared__ alignas(16) bf16 As[128*32];
  __shared__ alignas(16) bf16 Bs[128*32];
  const int tid = threadIdx.x;
  const int wave = tid >> 6, lane = tid & 63;
  const int lo = lane & 15, hi = lane >> 4;
  const int hi2 = hi ^ ((lo >> 1) & 3);
  const int wr = wave >> 1, wc = wave & 1;
  const int row0 = blockIdx.x * 128, col0 = blockIdx.y * 128;
  const int srow  = lane >> 2;
  const int skoff = (((lane & 3) ^ ((lane >> 3) & 3)) << 3);

  f32x4 acc[4][4] = {};

  for (int k0 = 0; k0 < K; k0 += 32) {
#pragma unroll
    for (int c = 0; c < 2; ++c) {
      const int seg = c*4 + wave;
      int ra = row0 + seg*16 + srow; ra = ra < M ? ra : M-1;
      llds16(A + (long)ra*lda + (k0 + skoff), (char*)As + seg*1024);
      int rb = col0 + seg*16 + srow; rb = rb < N ? rb : N-1;
      llds16(Bt + (long)rb*ldb + (k0 + skoff), (char*)Bs + seg*1024);
    }
    __syncthreads();
    bf16x8 af[4], bfv[4];
#pragma unroll
    for (int m = 0; m < 4; m++)
      af[m] = *(const bf16x8*)((const char*)As + (wr*64 + m*16 + lo)*64 + hi2*16);
#pragma unroll
    for (int n = 0; n < 4; n++)
      bfv[n] = *(const bf16x8*)((const char*)Bs + (wc*64 + n*16 + lo)*64 + hi2*16);
#pragma unroll
    for (int m = 0; m < 4; m++)
#pragma unroll
      for (int n = 0; n < 4; n++)
        acc[m][n] = __builtin_amdgcn_mfma_f32_16x16x32_bf16(af[m], bfv[n], acc[m][n], 0, 0, 0);
    __syncthreads();
  }

#pragma unroll
  for (int m = 0; m < 4; m++) {
    const int rbase = row0 + wr*64 + m*16 + hi*4;
#pragma unroll
    for (int n = 0; n < 4; n++) {
      const int cc = col0 + wc*64 + n*16 + lo;
      if (cc >= N) continue;
      const float bb = bias ? bias[cc] : 0.0f;
#pragma unroll
      for (int j = 0; j < 4; j++) {
        const int rr = rbase + j;
        if (rr < M) store_out(&C[(long)rr*ldc + cc], acc[m][n][j] + bb);
      }
    }
  }
}

// ---------------- weight prep: W[K,N] f32 -> Wt[N,K] bf16, z-indexed up to 4 pairs ----------------
__global__ __launch_bounds__(256) void wprep4_kernel(
    const float* W0, const float* W1, const float* W2, const float* W3,
    bf16* T0, bf16* T1, bf16* T2, bf16* T3, int K, int N)
{
  const int z = blockIdx.z;
  const float* W = z == 0 ? W0 : z == 1 ? W1 : z == 2 ? W2 : W3;
  bf16* T = z == 0 ? T0 : z == 1 ? T1 : z == 2 ? T2 : T3;
  __shared__ bf16 t[32][33];
  const int k0 = blockIdx.x * 32, n0 = blockIdx.y * 32;
  const int tx = threadIdx.x & 31, ty = threadIdx.x >> 5;
#pragma unroll
  for (int i = 0; i < 4; i++)
    t[ty + i*8][tx] = __float2bfloat16(W[(long)(k0 + ty + i*8)*N + n0 + tx]);
  __syncthreads();
#pragma unroll
  for (int i = 0; i < 4; i++)
    T[(long)(n0 + ty + i*8)*K + k0 + tx] = t[tx][ty + i*8];
}

// ---------------- bf16 transpose with zero-pad: in[R x Cc (ld inLD)] -> out[Cc x outLD] ----------------
__global__ __launch_bounds__(256) void transpose_pad_kernel(
    const bf16* __restrict__ in, bf16* __restrict__ out,
    int R, int Cc, int inLD, int outLD, long inBatch, long outBatch)
{
  in  += (long)blockIdx.z * inBatch;
  out += (long)blockIdx.z * outBatch;
  __shared__ bf16 t[32][33];
  const int r0 = blockIdx.x * 32, c0 = blockIdx.y * 32;
  const int tx = threadIdx.x & 31, ty = threadIdx.x >> 5;
#pragma unroll
  for (int i = 0; i < 4; i++) {
    const int r = r0 + ty + i*8;
    bf16 v = __float2bfloat16(0.0f);
    if (r < R) v = in[(long)r*inLD + c0 + tx];
    t[ty + i*8][tx] = v;
  }
  __syncthreads();
#pragma unroll
  for (int i = 0; i < 4; i++) {
    const int oc = r0 + tx;
    const int orow = c0 + ty + i*8;
    if (oc < outLD) out[(long)orow*outLD + oc] = t[tx][ty + i*8];
  }
}

// ---------------- bias concat (up to 3) ----------------
__global__ __launch_bounds__(256) void concat_bias_kernel(
    const float* a, const float* b, const float* c, int n1, int n2, int n3, float* out)
{
  const int i = blockIdx.x * 256 + threadIdx.x;
  if (i >= n1 + n2 + n3) return;
  out[i] = i < n1 ? a[i] : (i < n1 + n2 ? b[i - n1] : c[i - n1 - n2]);
}

// ---------------- embedding + sinusoidal positional encoding ----------------
__global__ __launch_bounds__(256) void embed_kernel(
    const int* __restrict__ tok, const float* __restrict__ tbl,
    float* __restrict__ xf, bf16* __restrict__ xb)
{
  const int row = blockIdx.x;
  const int s = row & 511;
  const float pos = (float)s;
  const float* te = tbl + (long)tok[row] * 1024;
  const int d0 = threadIdx.x * 4;
  float4 v = *(const float4*)(te + d0);
  float o[4] = {v.x, v.y, v.z, v.w};
  // 10000^(-i2/1024) = exp2(-i2 * log2(10000)/1024)
#pragma unroll
  for (int k = 0; k < 4; k++) {
    const int d = d0 + k;
    const int i2 = d & ~1;
    const float ang = pos * exp2f((float)i2 * -0.0129762816f);
    o[k] += (d & 1) ? __cosf(ang) : __sinf(ang);
  }
  *(float4*)(xf + (long)row*1024 + d0) = make_float4(o[0], o[1], o[2], o[3]);
#pragma unroll
  for (int k = 0; k < 4; k++) xb[(long)row*1024 + d0 + k] = __float2bfloat16(o[k]);
}

// ---------------- f32 -> bf16 copy ----------------
__global__ __launch_bounds__(256) void cvt_bf16_kernel(const float* __restrict__ in, bf16* __restrict__ out, long n)
{
  long i = (long)blockIdx.x * blockDim.x + threadIdx.x;
  if (i < n) out[i] = __float2bfloat16(in[i]);
}

// ---------------- causal softmax over scores [B*S rows][512] ----------------
__global__ __launch_bounds__(64) void softmax_causal_kernel(
    const float* __restrict__ Sc, bf16* __restrict__ P)
{
  const int row = blockIdx.x;
  const int q = row & 511;
  const float* srow = Sc + (long)row * 512;
  bf16* prow = P + (long)row * 512;
  const int lane = threadIdx.x;
  const float scale = 0.03125f;
  float mx = -1e30f;
  for (int j = lane; j <= q; j += 64) mx = fmaxf(mx, srow[j]);
  mx = wredmax(mx);
  float sum = 0.0f;
  for (int j = lane; j <= q; j += 64) sum += expf((srow[j] - mx) * scale);
  sum = wredsum(sum);
  const float inv = 1.0f / sum;
  for (int j = lane; j < 512; j += 64) {
    float p = (j <= q) ? expf((srow[j] - mx) * scale) * inv : 0.0f;
    prow[j] = __float2bfloat16(p);
  }
}

// ---------------- cross softmax: rows of 197 valid (ld 224) ----------------
__global__ __launch_bounds__(64) void softmax_cross_kernel(
    const float* __restrict__ Sc, bf16* __restrict__ P)
{
  const int row = blockIdx.x;
  const float* srow = Sc + (long)row * 224;
  bf16* prow = P + (long)row * 224;
  const int lane = threadIdx.x;
  const float scale = 0.03125f;
  float mx = -1e30f;
  for (int j = lane; j < 197; j += 64) mx = fmaxf(mx, srow[j]);
  mx = wredmax(mx);
  float sum = 0.0f;
  for (int j = lane; j < 197; j += 64) sum += expf((srow[j] - mx) * scale);
  sum = wredsum(sum);
  const float inv = 1.0f / sum;
  for (int j = lane; j < 224; j += 64) {
    float p = (j < 197) ? expf((srow[j] - mx) * scale) * inv : 0.0f;
    prow[j] = __float2bfloat16(p);
  }
}

// ---------------- add residual + LayerNorm; write f32 (optional) + bf16 ----------------
__global__ __launch_bounds__(256) void add_ln_kernel(
    const float* __restrict__ Acc, const float* __restrict__ Res,
    const float* __restrict__ g, const float* __restrict__ b,
    float* __restrict__ outf, bf16* __restrict__ outb)
{
  const int row = blockIdx.x;
  const float* a = Acc + (long)row * 1024;
  const float* r = Res + (long)row * 1024;
  float vals[4], s = 0.0f, ss = 0.0f;
#pragma unroll
  for (int i = 0; i < 4; i++) {
    const int d = threadIdx.x + i*256;
    const float v = a[d] + r[d];
    vals[i] = v; s += v; ss += v*v;
  }
  s = wredsum(s); ss = wredsum(ss);
  __shared__ float sh[8];
  const int wave = threadIdx.x >> 6, lane = threadIdx.x & 63;
  if (lane == 0) { sh[wave] = s; sh[wave+4] = ss; }
  __syncthreads();
  s  = sh[0] + sh[1] + sh[2] + sh[3];
  ss = sh[4] + sh[5] + sh[6] + sh[7];
  const float mean = s * (1.0f/1024.0f);
  const float var  = ss * (1.0f/1024.0f) - mean*mean;
  const float inv  = rsqrtf(var + 1e-5f);
#pragma unroll
  for (int i = 0; i < 4; i++) {
    const int d = threadIdx.x + i*256;
    const float y = (vals[i] - mean) * inv * g[d] + b[d];
    if (outf) outf[(long)row*1024 + d] = y;
    outb[(long)row*1024 + d] = __float2bfloat16(y);
  }
}

// =======================================================================================
extern "C" void kernel_launch(void* const* d_in, const int* in_sizes, int n_in,
                              void* d_out, int out_size, void* d_ws, size_t ws_size,
                              hipStream_t stream) {
  const int*   tokens = (const int*)  d_in[0];
  const float* img    = (const float*)d_in[1];
  const float* emb    = (const float*)d_in[2];
  const float* Wq1    = (const float*)d_in[3];
  const float* bq1    = (const float*)d_in[4];
  const float* Wk1    = (const float*)d_in[5];
  const float* bk1    = (const float*)d_in[6];
  const float* Wv1    = (const float*)d_in[7];
  const float* bv1    = (const float*)d_in[8];
  const float* g1     = (const float*)d_in[9];
  const float* b1     = (const float*)d_in[10];
  const float* Wq2    = (const float*)d_in[11];
  const float* bq2    = (const float*)d_in[12];
  const float* Wk2    = (const float*)d_in[13];
  const float* bk2    = (const float*)d_in[14];
  const float* Wv2    = (const float*)d_in[15];
  const float* bv2    = (const float*)d_in[16];
  const float* g2     = (const float*)d_in[17];
  const float* b2     = (const float*)d_in[18];
  const float* Wp     = (const float*)d_in[19];
  const float* bp     = (const float*)d_in[20];
  float* out = (float*)d_out;

  const int B = 8, S = 512, D = 1024, DI = 768, NI = 197, NIP = 224, V = 32000;
  const int M = B * S;          // 4096
  const int MI = B * NI;        // 1576

  char* ws = (char*)d_ws;
  size_t off = 0;
  auto alloc = [&](size_t bytes) -> char* {
    char* p = ws + off; off += (bytes + 255) & ~(size_t)255; return p;
  };
  // NOTE: Wq1t/Wk1t/Wv1t contiguous (each 2MB, 256-aligned) -> fused QKV B-matrix [3072][1024].
  //       Wk2t/Wv2t contiguous (each 1.5MB) -> fused KV2 B-matrix [2048][768].
  bf16* Wq1t = (bf16*)alloc((size_t)D*D*2);
  bf16* Wk1t = (bf16*)alloc((size_t)D*D*2);
  bf16* Wv1t = (bf16*)alloc((size_t)D*D*2);
  bf16* Wq2t = (bf16*)alloc((size_t)D*D*2);
  bf16* Wk2t = (bf16*)alloc((size_t)D*DI*2);
  bf16* Wv2t = (bf16*)alloc((size_t)D*DI*2);
  bf16* Wpt  = (bf16*)alloc((size_t)V*D*2);
  float* bqkv= (float*)alloc((size_t)3*D*4);
  float* bkv2= (float*)alloc((size_t)2*D*4);
  float* xf  = (float*)alloc((size_t)M*D*4);
  bf16*  xb  = (bf16*) alloc((size_t)M*D*2);
  bf16*  imgb= (bf16*) alloc((size_t)MI*DI*2);
  bf16*  QKV = (bf16*) alloc((size_t)M*3*D*2);   // [M][3072]: Q | K | V
  bf16*  Vt  = (bf16*) alloc((size_t)M*D*2);
  float* sc1 = (float*)alloc((size_t)B*S*S*4);
  bf16*  P1  = (bf16*) alloc((size_t)B*S*S*2);
  float* ao1 = (float*)alloc((size_t)M*D*4);
  float* x2f = (float*)alloc((size_t)M*D*4);
  bf16*  x2b = (bf16*) alloc((size_t)M*D*2);
  bf16*  Q2  = (bf16*) alloc((size_t)M*D*2);
  bf16*  KV2 = (bf16*) alloc((size_t)MI*2*D*2);  // [MI][2048]: K2 | V2
  bf16*  V2t = (bf16*) alloc((size_t)B*D*NIP*2);
  float* sc2 = (float*)alloc((size_t)B*S*NIP*4);
  bf16*  P2  = (bf16*) alloc((size_t)B*S*NIP*2);
  float* ao2 = (float*)alloc((size_t)M*D*4);
  bf16*  x3b = (bf16*) alloc((size_t)M*D*2);
  (void)ws_size; (void)in_sizes; (void)n_in; (void)out_size;

  // --- weight prep (f32 [K,N] -> bf16 [N,K]) ---
  wprep4_kernel<<<dim3(D/32,  D/32, 4), 256, 0, stream>>>(Wq1, Wk1, Wv1, Wq2, Wq1t, Wk1t, Wv1t, Wq2t, D, D);
  wprep4_kernel<<<dim3(DI/32, D/32, 2), 256, 0, stream>>>(Wk2, Wv2, nullptr, nullptr, Wk2t, Wv2t, nullptr, nullptr, DI, D);
  wprep4_kernel<<<dim3(D/32,  V/32, 1), 256, 0, stream>>>(Wp, nullptr, nullptr, nullptr, Wpt, nullptr, nullptr, nullptr, D, V);
  concat_bias_kernel<<<(3*D+255)/256, 256, 0, stream>>>(bq1, bk1, bv1, D, D, D, bqkv);
  concat_bias_kernel<<<(2*D+255)/256, 256, 0, stream>>>(bk2, bv2, nullptr, D, D, 0, bkv2);

  // --- embed + img convert ---
  embed_kernel<<<M, 256, 0, stream>>>(tokens, emb, xf, xb);
  {
    long n = (long)MI * DI;
    cvt_bf16_kernel<<<(int)((n + 255)/256), 256, 0, stream>>>(img, imgb, n);
  }

  auto gemmF = [&](const bf16* A, const bf16* Bt, float* C, const float* bias,
                   int m, int n, int k, int lda, int ldb, int ldc,
                   long sA, long sB, long sC, int batch) {
    dim3 g((m+127)/128, (n+127)/128, batch);
    gemm_bt_kernel<float><<<g, 256, 0, stream>>>(A, Bt, C, bias, m, n, k, lda, ldb, ldc, sA, sB, sC);
  };
  auto gemmB = [&](const bf16* A, const bf16* Bt, bf16* C, const float* bias,
                   int m, int n, int k, int lda, int ldb, int ldc,
                   long sA, long sB, long sC, int batch) {
    dim3 g((m+127)/128, (n+127)/128, batch);
    gemm_bt_kernel<bf16><<<g, 256, 0, stream>>>(A, Bt, C, bias, m, n, k, lda, ldb, ldc, sA, sB, sC);
  };

  // --- block 1: causal self-attention (fused QKV GEMM via 256^2 kernel: grid 16x12=192) ---
  gemm256_kernel<bf16><<<dim3((M/256)*(3*D/256)), 512, 0, stream>>>(
      xb, Wq1t, QKV, bqkv, M, 3*D, D, D, D, 3*D);
  transpose_pad_kernel<<<dim3(S/32, D/32, B), 256, 0, stream>>>(
      QKV + 2*D, Vt, S, D, 3*D, S, (long)S*3*D, (long)D*S);
  gemmF(QKV, QKV + D, sc1, nullptr, S, S, D, 3*D, 3*D, S, (long)S*3*D, (long)S*3*D, (long)S*S, B);
  softmax_causal_kernel<<<M, 64, 0, stream>>>(sc1, P1);
  gemmF(P1, Vt, ao1, nullptr, S, D, S, S, S, D, (long)S*S, (long)D*S, (long)S*D, B);
  add_ln_kernel<<<M, 256, 0, stream>>>(ao1, xf, g1, b1, x2f, x2b);

  // --- block 2: cross-attention over image tokens (fused K2V2 GEMM: N=2048) ---
  gemmB(x2b, Wq2t, Q2, bq2, M, D, D, D, D, D, 0, 0, 0, 1);
  gemmB(imgb, Wk2t, KV2, bkv2, MI, 2*D, DI, DI, DI, 2*D, 0, 0, 0, 1);
  transpose_pad_kernel<<<dim3((NIP+31)/32, D/32, B), 256, 0, stream>>>(
      KV2 + D, V2t, NI, D, 2*D, NIP, (long)NI*2*D, (long)D*NIP);
  gemmF(Q2, KV2, sc2, nullptr, S, NI, D, D, 2*D, NIP, (long)S*D, (long)NI*2*D, (long)S*NIP, B);
  softmax_cross_kernel<<<M, 64, 0, stream>>>(sc2, P2);
  gemmF(P2, V2t, ao2, nullptr, S, D, NIP, NIP, NIP, D, (long)S*NIP, (long)D*NIP, (long)S*D, B);
  add_ln_kernel<<<M, 256, 0, stream>>>(ao2, x2f, g2, b2, nullptr, x3b);

  // --- vocab projection: R2 ring-4 256^2 kernel (grid 16x125 = 2000 blocks) ---
  gemm256_kernel<float><<<dim3((M/256)*(V/256)), 512, 0, stream>>>(
      x3b, Wpt, out, bp, M, V, D, D, D, V);
}